// Round 2
// baseline (285.283 us; speedup 1.0000x reference)
//
#include <hip/hip_runtime.h>

#define BB 2
#define HH 16
#define TT 2048
#define DD 1024
#define DH 64

typedef _Float16 half8 __attribute__((ext_vector_type(8)));
typedef _Float16 half4v __attribute__((ext_vector_type(4)));
typedef float f32x4 __attribute__((ext_vector_type(4)));

#define GLOAD(g, l)                                                        \
    __builtin_amdgcn_global_load_lds(                                      \
        (const __attribute__((address_space(1))) unsigned int*)(g),        \
        (__attribute__((address_space(3))) unsigned int*)(l), 16, 0, 0)

// ---------------------------------------------------------------------------
// Convert kernels (one-time, memory-bound, ~50 MB total traffic)
// ---------------------------------------------------------------------------
__global__ __launch_bounds__(256) void cvt_x_kernel(
    const float* __restrict__ x, _Float16* __restrict__ xh)
{
    size_t i = ((size_t)blockIdx.x * 256 + threadIdx.x) * 8;
    float4 a = *(const float4*)&x[i];
    float4 b = *(const float4*)&x[i + 4];
    half8 o;
    o[0] = (_Float16)a.x; o[1] = (_Float16)a.y; o[2] = (_Float16)a.z; o[3] = (_Float16)a.w;
    o[4] = (_Float16)b.x; o[5] = (_Float16)b.y; o[6] = (_Float16)b.z; o[7] = (_Float16)b.w;
    *(half8*)&xh[i] = o;
}

// W_{Q,K,V}[h][d][e] -> Wt[(m*1024 + h*64 + e)][d]  fp16  (B-operand layout)
__global__ __launch_bounds__(256) void cvt_wqkv_kernel(
    const float* __restrict__ Wq, const float* __restrict__ Wk,
    const float* __restrict__ Wv, _Float16* __restrict__ Wt)
{
    const int tid = threadIdx.x;
    const int d0 = blockIdx.x * 64;
    const int h = blockIdx.y;
    const int m = blockIdx.z;
    const float* __restrict__ W = (m == 0) ? Wq : (m == 1) ? Wk : Wv;

    __shared__ float ts[64][68];
    const int dr = tid >> 2, ec = (tid & 3) * 16;
    const float* p = W + ((size_t)h * DD + d0 + dr) * DH + ec;
    *(float4*)&ts[dr][ec + 0]  = *(const float4*)(p + 0);
    *(float4*)&ts[dr][ec + 4]  = *(const float4*)(p + 4);
    *(float4*)&ts[dr][ec + 8]  = *(const float4*)(p + 8);
    *(float4*)&ts[dr][ec + 12] = *(const float4*)(p + 12);
    __syncthreads();

    const int er = tid >> 2, dc = (tid & 3) * 16;
    size_t obase = ((size_t)m * 1024 + h * 64 + er) * 1024 + d0 + dc;
    half8 o;
#pragma unroll
    for (int j = 0; j < 8; ++j) o[j] = (_Float16)ts[dc + j][er];
    *(half8*)&Wt[obase] = o;
#pragma unroll
    for (int j = 0; j < 8; ++j) o[j] = (_Float16)ts[dc + 8 + j][er];
    *(half8*)&Wt[obase + 8] = o;
}

// W_output flat [1024(he)][1024(d)] -> Wot[d][he] fp16
__global__ __launch_bounds__(256) void cvt_wo_kernel(
    const float* __restrict__ Wo, _Float16* __restrict__ Wot)
{
    const int tid = threadIdx.x;
    const int r0 = blockIdx.x * 64;   // he
    const int c0 = blockIdx.y * 64;   // d

    __shared__ float ts[64][68];
    const int rr = tid >> 2, cc = (tid & 3) * 16;
    const float* p = Wo + (size_t)(r0 + rr) * 1024 + c0 + cc;
    *(float4*)&ts[rr][cc + 0]  = *(const float4*)(p + 0);
    *(float4*)&ts[rr][cc + 4]  = *(const float4*)(p + 4);
    *(float4*)&ts[rr][cc + 8]  = *(const float4*)(p + 8);
    *(float4*)&ts[rr][cc + 12] = *(const float4*)(p + 12);
    __syncthreads();

    const int er = tid >> 2, dc = (tid & 3) * 16;
    size_t obase = (size_t)(c0 + er) * 1024 + r0 + dc;
    half8 o;
#pragma unroll
    for (int j = 0; j < 8; ++j) o[j] = (_Float16)ts[dc + j][er];
    *(half8*)&Wot[obase] = o;
#pragma unroll
    for (int j = 0; j < 8; ++j) o[j] = (_Float16)ts[dc + 8 + j][er];
    *(half8*)&Wot[obase + 8] = o;
}

// ---------------------------------------------------------------------------
// MFMA GEMM core (m97 recipe): 128x128 tile, BK=64, global_load_lds w=16,
// XOR-swizzled unpadded LDS.
// ---------------------------------------------------------------------------
#define GEMM_MAIN(Aptr, Bptr, lda, ldb, KDIM)                                   \
    __shared__ _Float16 As[128 * 64];                                           \
    __shared__ _Float16 Bs[128 * 64];                                           \
    const int tid = threadIdx.x;                                                \
    const int wave = tid >> 6, lane = tid & 63;                                 \
    const int quad = lane >> 4, l15 = lane & 15;                                \
    const int rowBase = blockIdx.x * 128;                                       \
    const int colBase = blockIdx.y * 128;                                       \
    const int wr = (wave >> 1) * 64, wc = (wave & 1) * 64;                      \
    f32x4 acc[4][4];                                                            \
    _Pragma("unroll") for (int sm = 0; sm < 4; ++sm)                            \
        _Pragma("unroll") for (int sn = 0; sn < 4; ++sn)                        \
            acc[sm][sn] = f32x4{0.f, 0.f, 0.f, 0.f};                            \
    for (int k0 = 0; k0 < (KDIM); k0 += 64) {                                   \
        __syncthreads();                                                        \
        _Pragma("unroll") for (int i = 0; i < 4; ++i) {                         \
            int c = wave * 256 + i * 64 + lane;                                 \
            int row = c >> 3, c8 = c & 7;                                       \
            int sc = ((c8 ^ (row & 7)) << 3);                                   \
            GLOAD((Aptr) + (size_t)(rowBase + row) * (lda) + k0 + sc,           \
                  &As[(wave * 256 + i * 64) * 8]);                              \
            GLOAD((Bptr) + (size_t)(colBase + row) * (ldb) + k0 + sc,           \
                  &Bs[(wave * 256 + i * 64) * 8]);                              \
        }                                                                       \
        __syncthreads();                                                        \
        _Pragma("unroll") for (int kk = 0; kk < 2; ++kk) {                      \
            half8 af[4], bf[4];                                                 \
            _Pragma("unroll") for (int s = 0; s < 4; ++s) {                     \
                int rm = wr + s * 16 + l15;                                     \
                af[s] = *(const half8*)&As[rm * 64 +                            \
                        (((kk * 4 + quad) ^ (rm & 7)) << 3)];                   \
                int rn = wc + s * 16 + l15;                                     \
                bf[s] = *(const half8*)&Bs[rn * 64 +                            \
                        (((kk * 4 + quad) ^ (rn & 7)) << 3)];                   \
            }                                                                   \
            _Pragma("unroll") for (int sm = 0; sm < 4; ++sm)                    \
                _Pragma("unroll") for (int sn = 0; sn < 4; ++sn)                \
                    acc[sm][sn] = __builtin_amdgcn_mfma_f32_16x16x32_f16(       \
                        af[sm], bf[sn], acc[sm][sn], 0, 0, 0);                  \
        }                                                                       \
    }

// QKV: A = xh [4096][1024], B = Wt [3072][1024]. grid (32, 24).
// Q output pre-scaled by (1/sqrt(Dh))*log2(e) -> attention uses raw exp2.
__global__ __launch_bounds__(256) void qkv_gemm_kernel(
    const _Float16* __restrict__ xh, const _Float16* __restrict__ Wt,
    const float* __restrict__ bq, const float* __restrict__ bk, const float* __restrict__ bv,
    _Float16* __restrict__ qh, _Float16* __restrict__ kh, _Float16* __restrict__ vt)
{
    GEMM_MAIN(xh, Wt, 1024, 1024, 1024)

    const int m = colBase >> 10;            // 0=Q,1=K,2=V
    const int nIn = colBase & 1023;
    const float* __restrict__ bias = (m == 0) ? bq : (m == 1) ? bk : bv;
    const float sc_ = (m == 0) ? 0.1803368801f : 1.0f;   // 0.125 * log2(e)

    if (m < 2) {
        _Float16* __restrict__ out = (m == 0) ? qh : kh;
#pragma unroll
        for (int sn = 0; sn < 4; ++sn) {
            int n = nIn + wc + sn * 16 + l15;
            int hh = n >> 6, e = n & 63;
            float bv_ = bias[n];
#pragma unroll
            for (int sm = 0; sm < 4; ++sm)
#pragma unroll
                for (int reg = 0; reg < 4; ++reg) {
                    int t = rowBase + wr + sm * 16 + quad * 4 + reg;
                    int bb = t >> 11, tt = t & (TT - 1);
                    out[(((size_t)bb * HH + hh) * TT + tt) * DH + e] =
                        (_Float16)((acc[sm][sn][reg] + bv_) * sc_);
                }
        }
    } else {
#pragma unroll
        for (int sn = 0; sn < 4; ++sn) {
            int n = nIn + wc + sn * 16 + l15;
            int hh = n >> 6, e = n & 63;
            float bv_ = bias[n];
#pragma unroll
            for (int sm = 0; sm < 4; ++sm) {
                int t = rowBase + wr + sm * 16 + quad * 4;
                int bb = t >> 11, tt = t & (TT - 1);
                int tile = tt >> 6, tp = tt & 63;
                half4v o;
#pragma unroll
                for (int reg = 0; reg < 4; ++reg)
                    o[reg] = (_Float16)(acc[sm][sn][reg] + bv_);
                *(half4v*)&vt[(((size_t)bb * HH + hh) * 32 + tile) * 4096 +
                              (size_t)e * 64 + tp] = o;
            }
        }
    }
}

// out-proj: A = zh [4096][1024], B = Wot [1024][1024]. grid (32, 8). fp32 out.
__global__ __launch_bounds__(256) void out_gemm_kernel(
    const _Float16* __restrict__ zh, const _Float16* __restrict__ Wot,
    const float* __restrict__ bo, float* __restrict__ out)
{
    GEMM_MAIN(zh, Wot, 1024, 1024, 1024)

#pragma unroll
    for (int sn = 0; sn < 4; ++sn) {
        int d = colBase + wc + sn * 16 + l15;
        float b_ = bo[d];
#pragma unroll
        for (int sm = 0; sm < 4; ++sm)
#pragma unroll
            for (int reg = 0; reg < 4; ++reg) {
                int r = rowBase + wr + sm * 16 + quad * 4 + reg;
                out[(size_t)r * 1024 + d] = acc[sm][sn][reg] + b_;
            }
    }
}

// ---------------------------------------------------------------------------
// Causal flash attention v4: fp16 MFMA, 1024 threads (16 waves).
//  *** 2 blocks/CU ***: LDS cut 116 KB -> exactly 80 KB, VGPR pinned <=64 via
//  __launch_bounds__(1024, 8). 512 blocks all co-resident (2/CU); K/V
//  double-buffering dropped -- per-iter load latency is hidden by the OTHER
//  resident block's compute (occupancy-based hiding instead of prefetch).
//  - static pair balance: tile = bx<256 ? 15-(bx>>5) : (bx>>5)-8, so the
//    co-resident pair (c, c+256) under XCD round-robin dispatch does
//    (16-u)+(u+1) = 17 iter-units on every CU.
//  - split-K: waves 0-7 cols [s*128, s*128+64), waves 8-15 [+64, +128);
//    states merged via LDS at block end. Each wave owns one 16-row strip.
//  - row-max via 4x DPP row_ror (pure VALU); log2-domain softmax (Q
//    pre-scaled by 0.125*log2e, raw v_exp_f32); row-sum via MFMA-by-ones.
//  - ps compressed: XOR-swizzled [128][64] per split-K group (wave-private
//    rows -> no barrier needed around ps).
// LDS: qs 16K | ks 16K | vs 16K | ps 2x16K = 80 KB. Merge scratch overlays
// qs (mlB) and ks+vs (accB) after the loop.
// ---------------------------------------------------------------------------
#define ATTN_LDS (16384 + 16384 + 16384 + 2 * 16384)

__device__ __forceinline__ float rowmax16(float m) {
    int x;
    x = __builtin_amdgcn_update_dpp(__float_as_int(m), __float_as_int(m),
                                    0x121, 0xf, 0xf, false);   // row_ror:1
    m = fmaxf(m, __int_as_float(x));
    x = __builtin_amdgcn_update_dpp(__float_as_int(m), __float_as_int(m),
                                    0x122, 0xf, 0xf, false);   // row_ror:2
    m = fmaxf(m, __int_as_float(x));
    x = __builtin_amdgcn_update_dpp(__float_as_int(m), __float_as_int(m),
                                    0x124, 0xf, 0xf, false);   // row_ror:4
    m = fmaxf(m, __int_as_float(x));
    x = __builtin_amdgcn_update_dpp(__float_as_int(m), __float_as_int(m),
                                    0x128, 0xf, 0xf, false);   // row_ror:8
    m = fmaxf(m, __int_as_float(x));
    return m;
}

__global__ __launch_bounds__(1024, 8) void attn_kernel(
    const _Float16* __restrict__ qh, const _Float16* __restrict__ kh,
    const _Float16* __restrict__ vt, _Float16* __restrict__ zh)
{
    __shared__ __align__(16) char smem[ATTN_LDS];
    _Float16* qs = (_Float16*)smem;                    // [128][64] swizzled (dead after hoist)
    _Float16* ks = (_Float16*)(smem + 16384);          // [128][64] swizzled
    _Float16* vs = (_Float16*)(smem + 32768);          // [128][64] swizzled
    float* mlB  = (float*)smem;                        // merge scratch (1 KB, over qs)
    float* accB = (float*)(smem + 16384);              // merge scratch (32 KB, over ks+vs)

    const int tid  = threadIdx.x;          // 0..1023
    const int wave = tid >> 6;             // 0..15
    const int lane = tid & 63;
    const int quad = lane >> 4;
    const int l15  = lane & 15;
    const int g    = wave >> 3;            // split-K group
    const int wr   = wave & 7;             // 16-row strip

    const int bx   = blockIdx.x;           // 0..511
    const int tile = (bx < 256) ? 15 - (bx >> 5) : (bx >> 5) - 8;
    const int idx  = bx & 31;
    const int h    = idx & 15;
    const int b    = idx >> 4;

    const int Q0 = tile * 128;
    const int niter = tile + 1;

    _Float16* ps = (_Float16*)(smem + 49152 + g * 16384);  // [128][64] swizzled

    const size_t headBase = ((size_t)b * HH + h) * (size_t)(TT * DH);
    const _Float16* qp  = qh + headBase + (size_t)Q0 * 64;
    const _Float16* kp  = kh + headBase;
    const _Float16* vtp = vt + ((size_t)b * HH + h) * 32 * 4096;

    half8 ones;
#pragma unroll
    for (int i = 0; i < 8; ++i) ones[i] = (_Float16)1.0f;

    // staging geometry: 1024 threads x 16B = 128 rows x 64 halfs, swizzled src
    const int srow = tid >> 3, sc8 = tid & 7;
    const size_t soff = (size_t)srow * 64 + ((sc8 ^ (srow & 7)) << 3);

    // stage k-rows [s*128, s*128+128) of K and V (single buffer each)
    auto stage_kv = [&](int s) {
        GLOAD(kp + (size_t)s * 8192 + soff, &ks[wave * 512]);
        GLOAD(vtp + (size_t)s * 8192 + soff, &vs[wave * 512]);
    };

    // prologue: stage Q + first K/V
    GLOAD(qp + soff, &qs[wave * 512]);
    stage_kv(0);
    __syncthreads();

    // hoisted Q A-frags (wave's strip)
    const int rmq = wr * 16 + l15;
    const int swq = rmq & 7;
    half8 aq0 = *(const half8*)&qs[rmq * 64 + ((quad ^ swq) << 3)];
    half8 aq1 = *(const half8*)&qs[rmq * 64 + (((4 + quad) ^ swq) << 3)];

    f32x4 accO[4];
    float mrow[4], lsum[4];
#pragma unroll
    for (int j = 0; j < 4; ++j) {
        accO[j] = f32x4{0.f, 0.f, 0.f, 0.f};
        mrow[j] = -1e30f;
        lsum[j] = 0.f;
    }

    for (int s = 0; s < niter; ++s) {
        const _Float16* curK = &ks[g * 4096];
        const _Float16* curV = &vs[g * 4096];
        const int tileC0 = s * 128 + g * 64;

        // K B-frags
        half8 bk0[4], bk1[4];
#pragma unroll
        for (int j = 0; j < 4; ++j) {
            int rn = j * 16 + l15, sw = rn & 7;
            bk0[j] = *(const half8*)&curK[rn * 64 + ((quad ^ sw) << 3)];
            bk1[j] = *(const half8*)&curK[rn * 64 + (((4 + quad) ^ sw) << 3)];
        }

        // S = Q K^T (log2-domain logits)
        f32x4 S[4];
#pragma unroll
        for (int j = 0; j < 4; ++j) {
            f32x4 a = f32x4{0.f, 0.f, 0.f, 0.f};
            a = __builtin_amdgcn_mfma_f32_16x16x32_f16(aq0, bk0[j], a, 0, 0, 0);
            a = __builtin_amdgcn_mfma_f32_16x16x32_f16(aq1, bk1[j], a, 0, 0, 0);
            S[j] = a;
        }

        // causal mask (near-diagonal strips only)
        const int rowMin = Q0 + wr * 16;
        if (tileC0 + 63 > rowMin) {
#pragma unroll
            for (int j = 0; j < 4; ++j) {
                int col = tileC0 + j * 16 + l15;
#pragma unroll
                for (int reg = 0; reg < 4; ++reg)
                    if (col > rowMin + quad * 4 + reg) S[j][reg] = -1e30f;
            }
        }

        // online softmax (exp2 domain, DPP row-max)
#pragma unroll
        for (int reg = 0; reg < 4; ++reg) {
            float mt = fmaxf(fmaxf(S[0][reg], S[1][reg]),
                             fmaxf(S[2][reg], S[3][reg]));
            mt = rowmax16(mt);
            float mnew = fmaxf(mrow[reg], mt);
            float alpha = __builtin_amdgcn_exp2f(mrow[reg] - mnew);
            mrow[reg] = mnew;
            lsum[reg] *= alpha;
#pragma unroll
            for (int j = 0; j < 4; ++j) {
                float sv = S[j][reg];
                float pv = __builtin_amdgcn_exp2f(sv - mnew);
                pv = (sv < -5e29f) ? 0.f : pv;   // all-masked-tile guard
                S[j][reg] = pv;
                accO[j][reg] *= alpha;
            }
        }
        // P write (XOR-swizzled [128][64]; wave-private rows)
        const int prow = wr * 16 + quad * 4;
#pragma unroll
        for (int reg = 0; reg < 4; ++reg) {
            const int row = prow + reg;
            const int sw = (row & 7) << 3;
#pragma unroll
            for (int j = 0; j < 4; ++j)
                ps[row * 64 + ((j * 16 + l15) ^ sw)] = (_Float16)S[j][reg];
        }

        // P A-frags (swizzle-compatible b128 reads; same-wave DS ordering)
        half8 ap0 = *(const half8*)&ps[rmq * 64 + ((quad ^ swq) << 3)];
        half8 ap1 = *(const half8*)&ps[rmq * 64 + (((4 + quad) ^ swq) << 3)];

        // row-sum via MFMA-by-ones
        {
            f32x4 psum = f32x4{0.f, 0.f, 0.f, 0.f};
            psum = __builtin_amdgcn_mfma_f32_16x16x32_f16(ap0, ones, psum, 0, 0, 0);
            psum = __builtin_amdgcn_mfma_f32_16x16x32_f16(ap1, ones, psum, 0, 0, 0);
#pragma unroll
            for (int reg = 0; reg < 4; ++reg) lsum[reg] += psum[reg];
        }

        // O += P V
#pragma unroll
        for (int j = 0; j < 4; ++j) {
            int rn = j * 16 + l15, sw = rn & 7;
            half8 bv0 = *(const half8*)&curV[rn * 64 + ((quad ^ sw) << 3)];
            half8 bv1 = *(const half8*)&curV[rn * 64 + (((4 + quad) ^ sw) << 3)];
            accO[j] = __builtin_amdgcn_mfma_f32_16x16x32_f16(ap0, bv0, accO[j], 0, 0, 0);
            accO[j] = __builtin_amdgcn_mfma_f32_16x16x32_f16(ap1, bv1, accO[j], 0, 0, 0);
        }

        __syncthreads();                    // all waves done reading ks/vs
        if (s + 1 < niter) {
            stage_kv(s + 1);
            __syncthreads();                // vmcnt drained -> K/V ready
        }
    }

    // ---- merge the two split-K states and store ----
    const int r0 = wr * 16 + quad * 4;
    if (g == 1) {
#pragma unroll
        for (int j = 0; j < 4; ++j)
#pragma unroll
            for (int reg = 0; reg < 4; ++reg)
                accB[(r0 + reg) * 64 + j * 16 + l15] = accO[j][reg];
        if (l15 == 0) {
#pragma unroll
            for (int reg = 0; reg < 4; ++reg) {
                mlB[r0 + reg] = mrow[reg];
                mlB[128 + r0 + reg] = lsum[reg];
            }
        }
    }
    __syncthreads();
    if (g == 0) {
#pragma unroll
        for (int reg = 0; reg < 4; ++reg) {
            const int r = r0 + reg;
            float mb = mlB[r], lb = mlB[128 + r];
            float m = fmaxf(mrow[reg], mb);
            float ea = __builtin_amdgcn_exp2f(mrow[reg] - m);
            float eb = __builtin_amdgcn_exp2f(mb - m);
            float inv = 1.f / (ea * lsum[reg] + eb * lb);
            int t = Q0 + r;
            size_t rowOff = ((size_t)b * TT + t) * DD + h * DH;
#pragma unroll
            for (int j = 0; j < 4; ++j) {
                float ob = accB[r * 64 + j * 16 + l15];
                zh[rowOff + j * 16 + l15] =
                    (_Float16)((ea * accO[j][reg] + eb * ob) * inv);
            }
        }
    }
}

extern "C" void kernel_launch(void* const* d_in, const int* in_sizes, int n_in,
                              void* d_out, int out_size, void* d_ws, size_t ws_size,
                              hipStream_t stream) {
    const float* x  = (const float*)d_in[0];
    const float* Wq = (const float*)d_in[1];
    const float* Wk = (const float*)d_in[2];
    const float* Wv = (const float*)d_in[3];
    const float* Wo = (const float*)d_in[4];
    const float* bq = (const float*)d_in[5];
    const float* bk = (const float*)d_in[6];
    const float* bv = (const float*)d_in[7];
    const float* bo = (const float*)d_in[8];
    float* out = (float*)d_out;

    const size_t MB = 1u << 20;
    char* wsb = (char*)d_ws;
    _Float16* xh  = (_Float16*)(wsb + 0 * MB);    //  8 MB  [4096][1024]
    _Float16* Wt  = (_Float16*)(wsb + 8 * MB);    //  6 MB  [3072][1024]
    _Float16* Wot = (_Float16*)(wsb + 14 * MB);   //  2 MB  [1024][1024]
    _Float16* qh  = (_Float16*)(wsb + 16 * MB);   //  8 MB  [b][h][t][e] (log2-domain scale)
    _Float16* kh  = (_Float16*)(wsb + 24 * MB);   //  8 MB
    _Float16* vt  = (_Float16*)(wsb + 32 * MB);   //  8 MB  [b][h][tile][e][t']
    _Float16* zh  = (_Float16*)(wsb + 40 * MB);   //  8 MB  [4096][1024]

    cvt_x_kernel<<<2048, 256, 0, stream>>>(x, xh);
    cvt_wqkv_kernel<<<dim3(16, 16, 3), 256, 0, stream>>>(Wq, Wk, Wv, Wt);
    cvt_wo_kernel<<<dim3(16, 16), 256, 0, stream>>>(Wo, Wot);
    qkv_gemm_kernel<<<dim3(32, 24), 256, 0, stream>>>(xh, Wt, bq, bk, bv, qh, kh, vt);
    attn_kernel<<<512, 1024, 0, stream>>>(qh, kh, vt, zh);
    out_gemm_kernel<<<dim3(32, 8), 256, 0, stream>>>(zh, Wot, bo, out);
}

// Round 3
// 203.120 us; speedup vs baseline: 1.4045x; 1.4045x over previous
//
#include <hip/hip_runtime.h>

#define BB 2
#define HH 16
#define TT 2048
#define DD 1024
#define DH 64

typedef _Float16 half8 __attribute__((ext_vector_type(8)));
typedef _Float16 half4v __attribute__((ext_vector_type(4)));
typedef float f32x4 __attribute__((ext_vector_type(4)));

#define GLOAD(g, l)                                                        \
    __builtin_amdgcn_global_load_lds(                                      \
        (const __attribute__((address_space(1))) unsigned int*)(g),        \
        (__attribute__((address_space(3))) unsigned int*)(l), 16, 0, 0)

// ---------------------------------------------------------------------------
// Convert kernels (one-time, memory-bound, ~50 MB total traffic)
// ---------------------------------------------------------------------------
__global__ __launch_bounds__(256) void cvt_x_kernel(
    const float* __restrict__ x, _Float16* __restrict__ xh)
{
    size_t i = ((size_t)blockIdx.x * 256 + threadIdx.x) * 8;
    float4 a = *(const float4*)&x[i];
    float4 b = *(const float4*)&x[i + 4];
    half8 o;
    o[0] = (_Float16)a.x; o[1] = (_Float16)a.y; o[2] = (_Float16)a.z; o[3] = (_Float16)a.w;
    o[4] = (_Float16)b.x; o[5] = (_Float16)b.y; o[6] = (_Float16)b.z; o[7] = (_Float16)b.w;
    *(half8*)&xh[i] = o;
}

// W_{Q,K,V}[h][d][e] -> Wt[(m*1024 + h*64 + e)][d]  fp16  (B-operand layout)
__global__ __launch_bounds__(256) void cvt_wqkv_kernel(
    const float* __restrict__ Wq, const float* __restrict__ Wk,
    const float* __restrict__ Wv, _Float16* __restrict__ Wt)
{
    const int tid = threadIdx.x;
    const int d0 = blockIdx.x * 64;
    const int h = blockIdx.y;
    const int m = blockIdx.z;
    const float* __restrict__ W = (m == 0) ? Wq : (m == 1) ? Wk : Wv;

    __shared__ float ts[64][68];
    const int dr = tid >> 2, ec = (tid & 3) * 16;
    const float* p = W + ((size_t)h * DD + d0 + dr) * DH + ec;
    *(float4*)&ts[dr][ec + 0]  = *(const float4*)(p + 0);
    *(float4*)&ts[dr][ec + 4]  = *(const float4*)(p + 4);
    *(float4*)&ts[dr][ec + 8]  = *(const float4*)(p + 8);
    *(float4*)&ts[dr][ec + 12] = *(const float4*)(p + 12);
    __syncthreads();

    const int er = tid >> 2, dc = (tid & 3) * 16;
    size_t obase = ((size_t)m * 1024 + h * 64 + er) * 1024 + d0 + dc;
    half8 o;
#pragma unroll
    for (int j = 0; j < 8; ++j) o[j] = (_Float16)ts[dc + j][er];
    *(half8*)&Wt[obase] = o;
#pragma unroll
    for (int j = 0; j < 8; ++j) o[j] = (_Float16)ts[dc + 8 + j][er];
    *(half8*)&Wt[obase + 8] = o;
}

// W_output flat [1024(he)][1024(d)] -> Wot[d][he] fp16
__global__ __launch_bounds__(256) void cvt_wo_kernel(
    const float* __restrict__ Wo, _Float16* __restrict__ Wot)
{
    const int tid = threadIdx.x;
    const int r0 = blockIdx.x * 64;   // he
    const int c0 = blockIdx.y * 64;   // d

    __shared__ float ts[64][68];
    const int rr = tid >> 2, cc = (tid & 3) * 16;
    const float* p = Wo + (size_t)(r0 + rr) * 1024 + c0 + cc;
    *(float4*)&ts[rr][cc + 0]  = *(const float4*)(p + 0);
    *(float4*)&ts[rr][cc + 4]  = *(const float4*)(p + 4);
    *(float4*)&ts[rr][cc + 8]  = *(const float4*)(p + 8);
    *(float4*)&ts[rr][cc + 12] = *(const float4*)(p + 12);
    __syncthreads();

    const int er = tid >> 2, dc = (tid & 3) * 16;
    size_t obase = (size_t)(c0 + er) * 1024 + r0 + dc;
    half8 o;
#pragma unroll
    for (int j = 0; j < 8; ++j) o[j] = (_Float16)ts[dc + j][er];
    *(half8*)&Wot[obase] = o;
#pragma unroll
    for (int j = 0; j < 8; ++j) o[j] = (_Float16)ts[dc + 8 + j][er];
    *(half8*)&Wot[obase + 8] = o;
}

// ---------------------------------------------------------------------------
// MFMA GEMM core (m97 recipe): 128x128 tile, BK=64, global_load_lds w=16,
// XOR-swizzled unpadded LDS. RB/CB are block-tile indices (XCD-swizzled by
// the caller for L2 locality).
// ---------------------------------------------------------------------------
#define GEMM_MAIN(Aptr, Bptr, lda, ldb, KDIM, RB, CB)                           \
    __shared__ _Float16 As[128 * 64];                                           \
    __shared__ _Float16 Bs[128 * 64];                                           \
    const int tid = threadIdx.x;                                                \
    const int wave = tid >> 6, lane = tid & 63;                                 \
    const int quad = lane >> 4, l15 = lane & 15;                                \
    const int rowBase = (RB) * 128;                                             \
    const int colBase = (CB) * 128;                                             \
    const int wr = (wave >> 1) * 64, wc = (wave & 1) * 64;                      \
    f32x4 acc[4][4];                                                            \
    _Pragma("unroll") for (int sm = 0; sm < 4; ++sm)                            \
        _Pragma("unroll") for (int sn = 0; sn < 4; ++sn)                        \
            acc[sm][sn] = f32x4{0.f, 0.f, 0.f, 0.f};                            \
    for (int k0 = 0; k0 < (KDIM); k0 += 64) {                                   \
        __syncthreads();                                                        \
        _Pragma("unroll") for (int i = 0; i < 4; ++i) {                         \
            int c = wave * 256 + i * 64 + lane;                                 \
            int row = c >> 3, c8 = c & 7;                                       \
            int sc = ((c8 ^ (row & 7)) << 3);                                   \
            GLOAD((Aptr) + (size_t)(rowBase + row) * (lda) + k0 + sc,           \
                  &As[(wave * 256 + i * 64) * 8]);                              \
            GLOAD((Bptr) + (size_t)(colBase + row) * (ldb) + k0 + sc,           \
                  &Bs[(wave * 256 + i * 64) * 8]);                              \
        }                                                                       \
        __syncthreads();                                                        \
        _Pragma("unroll") for (int kk = 0; kk < 2; ++kk) {                      \
            half8 af[4], bf[4];                                                 \
            _Pragma("unroll") for (int s = 0; s < 4; ++s) {                     \
                int rm = wr + s * 16 + l15;                                     \
                af[s] = *(const half8*)&As[rm * 64 +                            \
                        (((kk * 4 + quad) ^ (rm & 7)) << 3)];                   \
                int rn = wc + s * 16 + l15;                                     \
                bf[s] = *(const half8*)&Bs[rn * 64 +                            \
                        (((kk * 4 + quad) ^ (rn & 7)) << 3)];                   \
            }                                                                   \
            _Pragma("unroll") for (int sm = 0; sm < 4; ++sm)                    \
                _Pragma("unroll") for (int sn = 0; sn < 4; ++sn)                \
                    acc[sm][sn] = __builtin_amdgcn_mfma_f32_16x16x32_f16(       \
                        af[sm], bf[sn], acc[sm][sn], 0, 0, 0);                  \
        }                                                                       \
    }

// QKV: A = xh [4096][1024], B = Wt [3072][1024]. grid (32, 24).
// Q output pre-scaled by (1/sqrt(Dh))*log2(e) -> attention uses raw exp2.
// XCD swizzle: 768 blocks -> 8 chunks of 96 (32 row-tiles x 3 col-panels);
// each XCD's B working set (768 KB) becomes L2-resident.
__global__ __launch_bounds__(256) void qkv_gemm_kernel(
    const _Float16* __restrict__ xh, const _Float16* __restrict__ Wt,
    const float* __restrict__ bq, const float* __restrict__ bk, const float* __restrict__ bv,
    _Float16* __restrict__ qh, _Float16* __restrict__ kh, _Float16* __restrict__ vt)
{
    const int lin = blockIdx.y * 32 + blockIdx.x;      // dispatch-linear id
    const int swz = (lin & 7) * 96 + (lin >> 3);       // bijective (768%8==0)
    GEMM_MAIN(xh, Wt, 1024, 1024, 1024, (swz & 31), (swz >> 5))

    const int m = colBase >> 10;            // 0=Q,1=K,2=V
    const int nIn = colBase & 1023;
    const float* __restrict__ bias = (m == 0) ? bq : (m == 1) ? bk : bv;
    const float sc_ = (m == 0) ? 0.1803368801f : 1.0f;   // 0.125 * log2(e)

    if (m < 2) {
        _Float16* __restrict__ out = (m == 0) ? qh : kh;
#pragma unroll
        for (int sn = 0; sn < 4; ++sn) {
            int n = nIn + wc + sn * 16 + l15;
            int hh = n >> 6, e = n & 63;
            float bv_ = bias[n];
#pragma unroll
            for (int sm = 0; sm < 4; ++sm)
#pragma unroll
                for (int reg = 0; reg < 4; ++reg) {
                    int t = rowBase + wr + sm * 16 + quad * 4 + reg;
                    int bb = t >> 11, tt = t & (TT - 1);
                    out[(((size_t)bb * HH + hh) * TT + tt) * DH + e] =
                        (_Float16)((acc[sm][sn][reg] + bv_) * sc_);
                }
        }
    } else {
#pragma unroll
        for (int sn = 0; sn < 4; ++sn) {
            int n = nIn + wc + sn * 16 + l15;
            int hh = n >> 6, e = n & 63;
            float bv_ = bias[n];
#pragma unroll
            for (int sm = 0; sm < 4; ++sm) {
                int t = rowBase + wr + sm * 16 + quad * 4;
                int bb = t >> 11, tt = t & (TT - 1);
                int tile = tt >> 6, tp = tt & 63;
                half4v o;
#pragma unroll
                for (int reg = 0; reg < 4; ++reg)
                    o[reg] = (_Float16)(acc[sm][sn][reg] + bv_);
                *(half4v*)&vt[(((size_t)bb * HH + hh) * 32 + tile) * 4096 +
                              (size_t)e * 64 + tp] = o;
            }
        }
    }
}

// out-proj: A = zh [4096][1024], B = Wot [1024][1024]. grid (32, 8). fp32 out.
__global__ __launch_bounds__(256) void out_gemm_kernel(
    const _Float16* __restrict__ zh, const _Float16* __restrict__ Wot,
    const float* __restrict__ bo, float* __restrict__ out)
{
    const int lin = blockIdx.y * 32 + blockIdx.x;      // 0..255
    const int swz = (lin & 7) * 32 + (lin >> 3);       // bijective (256%8==0)
    GEMM_MAIN(zh, Wot, 1024, 1024, 1024, (swz & 31), (swz >> 5))

#pragma unroll
    for (int sn = 0; sn < 4; ++sn) {
        int d = colBase + wc + sn * 16 + l15;
        float b_ = bo[d];
#pragma unroll
        for (int sm = 0; sm < 4; ++sm)
#pragma unroll
            for (int reg = 0; reg < 4; ++reg) {
                int r = rowBase + wr + sm * 16 + quad * 4 + reg;
                out[(size_t)r * 1024 + d] = acc[sm][sn][reg] + b_;
            }
    }
}

// ---------------------------------------------------------------------------
// Causal flash attention (round-1 structure, reverted from the failed 80KB
// variant): fp16 MFMA, 1024 threads (16 waves = 4/SIMD), 1 block/CU.
//  - 512 one-tile blocks, heavy-first (tile = 15 - bx>>5): first 256 resident
//    blocks are the heavy half, light tiles backfill -> LPT dynamic balance.
//  - split-K: waves 0-7 even 64-col k-subtiles, waves 8-15 odd; states merged
//    via LDS at block end. Each wave owns one 16-row strip.
//  - row-max via 4x DPP row_ror (pure VALU); log2-domain softmax (Q
//    pre-scaled by 0.125*log2e, raw v_exp_f32); row-sum via MFMA-by-ones.
//  - quad-buffered K/V via global_load_lds; prefetch issued before compute.
//  - T5: s_setprio(1) around MFMA clusters (split-K groups + prefetch give
//    wave phase-diversity -> scheduler has something to arbitrate; +4-7%).
//  - NOTE round-2 lesson: 2 blocks/CU of this kernel is register-infeasible
//    (unified VGPR+AGPR budget 64/wave forces ~160 MB scratch spill).
// LDS: qs 16K | ks 2x16K | vs 2x16K | ps 2x18K = 116 KB -> 1 block/CU.
// ---------------------------------------------------------------------------
#define ATTN_LDS (16384 + 32768 + 32768 + 2 * 18432)

__device__ __forceinline__ float rowmax16(float m) {
    int x;
    x = __builtin_amdgcn_update_dpp(__float_as_int(m), __float_as_int(m),
                                    0x121, 0xf, 0xf, false);   // row_ror:1
    m = fmaxf(m, __int_as_float(x));
    x = __builtin_amdgcn_update_dpp(__float_as_int(m), __float_as_int(m),
                                    0x122, 0xf, 0xf, false);   // row_ror:2
    m = fmaxf(m, __int_as_float(x));
    x = __builtin_amdgcn_update_dpp(__float_as_int(m), __float_as_int(m),
                                    0x124, 0xf, 0xf, false);   // row_ror:4
    m = fmaxf(m, __int_as_float(x));
    x = __builtin_amdgcn_update_dpp(__float_as_int(m), __float_as_int(m),
                                    0x128, 0xf, 0xf, false);   // row_ror:8
    m = fmaxf(m, __int_as_float(x));
    return m;
}

__global__ __launch_bounds__(1024) void attn_kernel(
    const _Float16* __restrict__ qh, const _Float16* __restrict__ kh,
    const _Float16* __restrict__ vt, _Float16* __restrict__ zh)
{
    __shared__ __align__(16) char smem[ATTN_LDS];
    _Float16* qs = (_Float16*)smem;                    // [128][64] swizzled
    _Float16* ks = (_Float16*)(smem + 16384);          // [4][64][64] swizzled
    _Float16* vs = (_Float16*)(smem + 49152);          // [4][64][64] swizzled
    float* accB = (float*)(smem + 16384);              // merge scratch (32 KB)
    float* mlB  = (float*)(smem + 49152);              // merge scratch (1 KB)

    const int tid  = threadIdx.x;          // 0..1023
    const int wave = tid >> 6;             // 0..15
    const int lane = tid & 63;
    const int quad = lane >> 4;
    const int l15  = lane & 15;
    const int g    = wave >> 3;            // split-K group
    const int wr   = wave & 7;             // 16-row strip

    const int bx   = blockIdx.x;           // 0..511
    const int tile = 15 - (bx >> 5);       // heavy-first dispatch order
    const int idx  = bx & 31;
    const int h    = idx & 15;
    const int b    = idx >> 4;

    const int Q0 = tile * 128;
    const int niter = tile + 1;

    _Float16* ps = (_Float16*)(smem + 81920 + g * 18432);  // [128][72] padded

    const size_t headBase = ((size_t)b * HH + h) * (size_t)(TT * DH);
    const _Float16* qp  = qh + headBase + (size_t)Q0 * 64;
    const _Float16* kp  = kh + headBase;
    const _Float16* vtp = vt + ((size_t)b * HH + h) * 32 * 4096;

    half8 ones;
#pragma unroll
    for (int i = 0; i < 8; ++i) ones[i] = (_Float16)1.0f;

    // staging geometry: 1024 threads x 16B = 128 rows x 64 halfs, swizzled src
    const int srow = tid >> 3, sc8 = tid & 7;
    const size_t soff = (size_t)srow * 64 + ((sc8 ^ (srow & 7)) << 3);

    // stage k-rows [s*128, s*128+128) of K and V into parity (s&1)
    auto stage_kv = [&](int s) {
        GLOAD(kp + (size_t)s * 8192 + soff, &ks[(s & 1) * 8192 + wave * 512]);
        GLOAD(vtp + (size_t)s * 8192 + soff, &vs[(s & 1) * 8192 + wave * 512]);
    };

    // stage Q (16 KB) + first K/V pair
    GLOAD(qp + soff, &qs[wave * 512]);
    stage_kv(0);
    __syncthreads();

    // hoisted Q A-frags (wave's strip)
    const int rmq = wr * 16 + l15;
    const int swq = rmq & 7;
    half8 aq0 = *(const half8*)&qs[rmq * 64 + ((quad ^ swq) << 3)];
    half8 aq1 = *(const half8*)&qs[rmq * 64 + (((4 + quad) ^ swq) << 3)];

    f32x4 accO[4];
    float mrow[4], lsum[4];
#pragma unroll
    for (int j = 0; j < 4; ++j) {
        accO[j] = f32x4{0.f, 0.f, 0.f, 0.f};
        mrow[j] = -1e30f;
        lsum[j] = 0.f;
    }

    for (int s = 0; s < niter; ++s) {
        if (s + 1 < niter) stage_kv(s + 1);

        const _Float16* curK = &ks[((s & 1) * 2 + g) * 4096];
        const _Float16* curV = &vs[((s & 1) * 2 + g) * 4096];
        const int tileC0 = s * 128 + g * 64;

        // K B-frags
        half8 bk0[4], bk1[4];
#pragma unroll
        for (int j = 0; j < 4; ++j) {
            int rn = j * 16 + l15, sw = rn & 7;
            bk0[j] = *(const half8*)&curK[rn * 64 + ((quad ^ sw) << 3)];
            bk1[j] = *(const half8*)&curK[rn * 64 + (((4 + quad) ^ sw) << 3)];
        }

        // S = Q K^T (log2-domain logits)
        f32x4 S[4];
        __builtin_amdgcn_s_setprio(1);
#pragma unroll
        for (int j = 0; j < 4; ++j) {
            f32x4 a = f32x4{0.f, 0.f, 0.f, 0.f};
            a = __builtin_amdgcn_mfma_f32_16x16x32_f16(aq0, bk0[j], a, 0, 0, 0);
            a = __builtin_amdgcn_mfma_f32_16x16x32_f16(aq1, bk1[j], a, 0, 0, 0);
            S[j] = a;
        }
        __builtin_amdgcn_s_setprio(0);

        // causal mask (near-diagonal strips only)
        const int rowMin = Q0 + wr * 16;
        if (tileC0 + 63 > rowMin) {
#pragma unroll
            for (int j = 0; j < 4; ++j) {
                int col = tileC0 + j * 16 + l15;
#pragma unroll
                for (int reg = 0; reg < 4; ++reg)
                    if (col > rowMin + quad * 4 + reg) S[j][reg] = -1e30f;
            }
        }

        // online softmax (exp2 domain, DPP row-max)
#pragma unroll
        for (int reg = 0; reg < 4; ++reg) {
            float mt = fmaxf(fmaxf(S[0][reg], S[1][reg]),
                             fmaxf(S[2][reg], S[3][reg]));
            mt = rowmax16(mt);
            float mnew = fmaxf(mrow[reg], mt);
            float alpha = __builtin_amdgcn_exp2f(mrow[reg] - mnew);
            mrow[reg] = mnew;
            lsum[reg] *= alpha;
#pragma unroll
            for (int j = 0; j < 4; ++j) {
                float sv = S[j][reg];
                float pv = __builtin_amdgcn_exp2f(sv - mnew);
                pv = (sv < -5e29f) ? 0.f : pv;   // all-masked-tile guard
                S[j][reg] = pv;
                accO[j][reg] *= alpha;
            }
        }
        const int prow = wr * 16 + quad * 4;
#pragma unroll
        for (int j = 0; j < 4; ++j)
#pragma unroll
            for (int reg = 0; reg < 4; ++reg)
                ps[(prow + reg) * 72 + j * 16 + l15] = (_Float16)S[j][reg];

        // P A-frags (padded ps; per-wave DS ordering guarantees visibility)
        half8 ap0 = *(const half8*)&ps[rmq * 72 + quad * 8];
        half8 ap1 = *(const half8*)&ps[rmq * 72 + 32 + quad * 8];

        // row-sum via MFMA-by-ones; O += P V
        __builtin_amdgcn_s_setprio(1);
        {
            f32x4 psum = f32x4{0.f, 0.f, 0.f, 0.f};
            psum = __builtin_amdgcn_mfma_f32_16x16x32_f16(ap0, ones, psum, 0, 0, 0);
            psum = __builtin_amdgcn_mfma_f32_16x16x32_f16(ap1, ones, psum, 0, 0, 0);
#pragma unroll
            for (int reg = 0; reg < 4; ++reg) lsum[reg] += psum[reg];
        }
#pragma unroll
        for (int j = 0; j < 4; ++j) {
            int rn = j * 16 + l15, sw = rn & 7;
            half8 bv0 = *(const half8*)&curV[rn * 64 + ((quad ^ sw) << 3)];
            half8 bv1 = *(const half8*)&curV[rn * 64 + (((4 + quad) ^ sw) << 3)];
            accO[j] = __builtin_amdgcn_mfma_f32_16x16x32_f16(ap0, bv0, accO[j], 0, 0, 0);
            accO[j] = __builtin_amdgcn_mfma_f32_16x16x32_f16(ap1, bv1, accO[j], 0, 0, 0);
        }
        __builtin_amdgcn_s_setprio(0);

        __syncthreads();   // drains prefetch; protects buffer reuse
    }

    // ---- merge the two split-K states and store ----
    const int r0 = wr * 16 + quad * 4;
    if (g == 1) {
#pragma unroll
        for (int j = 0; j < 4; ++j)
#pragma unroll
            for (int reg = 0; reg < 4; ++reg)
                accB[(r0 + reg) * 64 + j * 16 + l15] = accO[j][reg];
        if (l15 == 0) {
#pragma unroll
            for (int reg = 0; reg < 4; ++reg) {
                mlB[r0 + reg] = mrow[reg];
                mlB[128 + r0 + reg] = lsum[reg];
            }
        }
    }
    __syncthreads();
    if (g == 0) {
#pragma unroll
        for (int reg = 0; reg < 4; ++reg) {
            const int r = r0 + reg;
            float mb = mlB[r], lb = mlB[128 + r];
            float m = fmaxf(mrow[reg], mb);
            float ea = __builtin_amdgcn_exp2f(mrow[reg] - m);
            float eb = __builtin_amdgcn_exp2f(mb - m);
            float inv = 1.f / (ea * lsum[reg] + eb * lb);
            int t = Q0 + r;
            size_t rowOff = ((size_t)b * TT + t) * DD + h * DH;
#pragma unroll
            for (int j = 0; j < 4; ++j) {
                float ob = accB[r * 64 + j * 16 + l15];
                zh[rowOff + j * 16 + l15] =
                    (_Float16)((ea * accO[j][reg] + eb * ob) * inv);
            }
        }
    }
}

extern "C" void kernel_launch(void* const* d_in, const int* in_sizes, int n_in,
                              void* d_out, int out_size, void* d_ws, size_t ws_size,
                              hipStream_t stream) {
    const float* x  = (const float*)d_in[0];
    const float* Wq = (const float*)d_in[1];
    const float* Wk = (const float*)d_in[2];
    const float* Wv = (const float*)d_in[3];
    const float* Wo = (const float*)d_in[4];
    const float* bq = (const float*)d_in[5];
    const float* bk = (const float*)d_in[6];
    const float* bv = (const float*)d_in[7];
    const float* bo = (const float*)d_in[8];
    float* out = (float*)d_out;

    const size_t MB = 1u << 20;
    char* wsb = (char*)d_ws;
    _Float16* xh  = (_Float16*)(wsb + 0 * MB);    //  8 MB  [4096][1024]
    _Float16* Wt  = (_Float16*)(wsb + 8 * MB);    //  6 MB  [3072][1024]
    _Float16* Wot = (_Float16*)(wsb + 14 * MB);   //  2 MB  [1024][1024]
    _Float16* qh  = (_Float16*)(wsb + 16 * MB);   //  8 MB  [b][h][t][e] (log2-domain scale)
    _Float16* kh  = (_Float16*)(wsb + 24 * MB);   //  8 MB
    _Float16* vt  = (_Float16*)(wsb + 32 * MB);   //  8 MB  [b][h][tile][e][t']
    _Float16* zh  = (_Float16*)(wsb + 40 * MB);   //  8 MB  [4096][1024]

    cvt_x_kernel<<<2048, 256, 0, stream>>>(x, xh);
    cvt_wqkv_kernel<<<dim3(16, 16, 3), 256, 0, stream>>>(Wq, Wk, Wv, Wt);
    cvt_wo_kernel<<<dim3(16, 16), 256, 0, stream>>>(Wo, Wot);
    qkv_gemm_kernel<<<dim3(32, 24), 256, 0, stream>>>(xh, Wt, bq, bk, bv, qh, kh, vt);
    attn_kernel<<<512, 1024, 0, stream>>>(qh, kh, vt, zh);
    out_gemm_kernel<<<dim3(32, 8), 256, 0, stream>>>(zh, Wot, bo, out);
}

// Round 4
// 187.560 us; speedup vs baseline: 1.5210x; 1.0830x over previous
//
#include <hip/hip_runtime.h>

#define BB 2
#define HH 16
#define TT 2048
#define DD 1024
#define DH 64

typedef _Float16 half8 __attribute__((ext_vector_type(8)));
typedef _Float16 half4v __attribute__((ext_vector_type(4)));
typedef float f32x4 __attribute__((ext_vector_type(4)));

#define GLOAD(g, l)                                                        \
    __builtin_amdgcn_global_load_lds(                                      \
        (const __attribute__((address_space(1))) unsigned int*)(g),        \
        (__attribute__((address_space(3))) unsigned int*)(l), 16, 0, 0)

// ---------------------------------------------------------------------------
// Merged convert kernel (one launch instead of three; saves 2 launch gaps).
//  blocks [0,2048):    x fp32 -> xh fp16 (flat)
//  blocks [2048,2816): W_{Q,K,V}[h][d][e] -> Wt[(m*1024+h*64+e)][d] fp16
//  blocks [2816,3072): W_output [he][d] -> Wot[d][he] fp16
// ---------------------------------------------------------------------------
__global__ __launch_bounds__(256) void cvt_all_kernel(
    const float* __restrict__ x, const float* __restrict__ Wq,
    const float* __restrict__ Wk, const float* __restrict__ Wv,
    const float* __restrict__ Wo, _Float16* __restrict__ xh,
    _Float16* __restrict__ Wt, _Float16* __restrict__ Wot)
{
    const int bid = blockIdx.x;
    const int tid = threadIdx.x;
    __shared__ float ts[64][68];

    if (bid < 2048) {
        size_t i = ((size_t)bid * 256 + tid) * 8;
        float4 a = *(const float4*)&x[i];
        float4 b = *(const float4*)&x[i + 4];
        half8 o;
        o[0] = (_Float16)a.x; o[1] = (_Float16)a.y; o[2] = (_Float16)a.z; o[3] = (_Float16)a.w;
        o[4] = (_Float16)b.x; o[5] = (_Float16)b.y; o[6] = (_Float16)b.z; o[7] = (_Float16)b.w;
        *(half8*)&xh[i] = o;
        return;
    }

    if (bid < 2816) {
        const int j = bid - 2048;
        const int m = j >> 8;              // 0..2
        const int rem = j & 255;
        const int h = rem >> 4;            // 0..15
        const int d0 = (rem & 15) * 64;
        const float* __restrict__ W = (m == 0) ? Wq : (m == 1) ? Wk : Wv;

        const int dr = tid >> 2, ec = (tid & 3) * 16;
        const float* p = W + ((size_t)h * DD + d0 + dr) * DH + ec;
        *(float4*)&ts[dr][ec + 0]  = *(const float4*)(p + 0);
        *(float4*)&ts[dr][ec + 4]  = *(const float4*)(p + 4);
        *(float4*)&ts[dr][ec + 8]  = *(const float4*)(p + 8);
        *(float4*)&ts[dr][ec + 12] = *(const float4*)(p + 12);
        __syncthreads();

        const int er = tid >> 2, dc = (tid & 3) * 16;
        size_t obase = ((size_t)m * 1024 + h * 64 + er) * 1024 + d0 + dc;
        half8 o;
#pragma unroll
        for (int jj = 0; jj < 8; ++jj) o[jj] = (_Float16)ts[dc + jj][er];
        *(half8*)&Wt[obase] = o;
#pragma unroll
        for (int jj = 0; jj < 8; ++jj) o[jj] = (_Float16)ts[dc + 8 + jj][er];
        *(half8*)&Wt[obase + 8] = o;
        return;
    }

    {
        const int j = bid - 2816;
        const int r0 = (j & 15) * 64;      // he
        const int c0 = (j >> 4) * 64;      // d

        const int rr = tid >> 2, cc = (tid & 3) * 16;
        const float* p = Wo + (size_t)(r0 + rr) * 1024 + c0 + cc;
        *(float4*)&ts[rr][cc + 0]  = *(const float4*)(p + 0);
        *(float4*)&ts[rr][cc + 4]  = *(const float4*)(p + 4);
        *(float4*)&ts[rr][cc + 8]  = *(const float4*)(p + 8);
        *(float4*)&ts[rr][cc + 12] = *(const float4*)(p + 12);
        __syncthreads();

        const int er = tid >> 2, dc = (tid & 3) * 16;
        size_t obase = (size_t)(c0 + er) * 1024 + r0 + dc;
        half8 o;
#pragma unroll
        for (int jj = 0; jj < 8; ++jj) o[jj] = (_Float16)ts[dc + jj][er];
        *(half8*)&Wot[obase] = o;
#pragma unroll
        for (int jj = 0; jj < 8; ++jj) o[jj] = (_Float16)ts[dc + 8 + jj][er];
        *(half8*)&Wot[obase + 8] = o;
    }
}

// ---------------------------------------------------------------------------
// MFMA GEMM core v2: 128x128 tile, BK=64, *** 512 threads (8 waves) ***,
// *** 2-phase double-buffered staging *** (T3-minimal: issue next tile's
// global_load_lds BEFORE computing current; ONE barrier per K-step --
// __syncthreads' vmcnt(0) drain doubles as the staging fence).
// Wave owns 32 rows x 64 cols -> acc[2][4]. LDS 64 KB (2 buf x (As+Bs)).
// Occupancy: out_gemm 1 block/CU -> 8 waves/CU (was 4); qkv 2 blocks/CU
// -> 16 waves/CU (was 12). XOR-swizzled unpadded LDS as before.
// ---------------------------------------------------------------------------
#define GEMM_MAIN8(Aptr, Bptr, lda, ldb, KDIM, RB, CB)                          \
    __shared__ _Float16 As[2][128 * 64];                                        \
    __shared__ _Float16 Bs[2][128 * 64];                                        \
    const int tid = threadIdx.x;                                                \
    const int wave = tid >> 6, lane = tid & 63;                                 \
    const int quad = lane >> 4, l15 = lane & 15;                                \
    const int rowBase = (RB) * 128;                                             \
    const int colBase = (CB) * 128;                                             \
    const int wrr = (wave >> 1) * 32, wcc = (wave & 1) * 64;                    \
    f32x4 acc[2][4];                                                            \
    _Pragma("unroll") for (int sm = 0; sm < 2; ++sm)                            \
        _Pragma("unroll") for (int sn = 0; sn < 4; ++sn)                        \
            acc[sm][sn] = f32x4{0.f, 0.f, 0.f, 0.f};                            \
    /* staging: 1024 16B-chunks per operand, 512 threads -> 2 passes */         \
    const int srow_[2] = { tid >> 3, (512 + tid) >> 3 };                        \
    const int sc8_ = tid & 7;                                                   \
    /* prologue: stage K-step 0 into buf 0 */                                   \
    _Pragma("unroll") for (int pass = 0; pass < 2; ++pass) {                    \
        int row = srow_[pass];                                                  \
        int sc = ((sc8_ ^ (row & 7)) << 3);                                     \
        GLOAD((Aptr) + (size_t)(rowBase + row) * (lda) + sc,                    \
              &As[0][(pass * 512 + tid) * 8]);                                  \
        GLOAD((Bptr) + (size_t)(colBase + row) * (ldb) + sc,                    \
              &Bs[0][(pass * 512 + tid) * 8]);                                  \
    }                                                                           \
    __syncthreads();                                                            \
    int cur = 0;                                                                \
    for (int k0 = 0; k0 < (KDIM); k0 += 64) {                                   \
        if (k0 + 64 < (KDIM)) {                                                 \
            _Pragma("unroll") for (int pass = 0; pass < 2; ++pass) {            \
                int row = srow_[pass];                                          \
                int sc = ((sc8_ ^ (row & 7)) << 3);                             \
                GLOAD((Aptr) + (size_t)(rowBase + row) * (lda) + k0 + 64 + sc,  \
                      &As[cur ^ 1][(pass * 512 + tid) * 8]);                    \
                GLOAD((Bptr) + (size_t)(colBase + row) * (ldb) + k0 + 64 + sc,  \
                      &Bs[cur ^ 1][(pass * 512 + tid) * 8]);                    \
            }                                                                   \
        }                                                                       \
        _Pragma("unroll") for (int kk = 0; kk < 2; ++kk) {                      \
            half8 af[2], bf[4];                                                 \
            _Pragma("unroll") for (int s = 0; s < 2; ++s) {                     \
                int rm = wrr + s * 16 + l15;                                    \
                af[s] = *(const half8*)&As[cur][rm * 64 +                       \
                        (((kk * 4 + quad) ^ (rm & 7)) << 3)];                   \
            }                                                                   \
            _Pragma("unroll") for (int s = 0; s < 4; ++s) {                     \
                int rn = wcc + s * 16 + l15;                                    \
                bf[s] = *(const half8*)&Bs[cur][rn * 64 +                       \
                        (((kk * 4 + quad) ^ (rn & 7)) << 3)];                   \
            }                                                                   \
            _Pragma("unroll") for (int sm = 0; sm < 2; ++sm)                    \
                _Pragma("unroll") for (int sn = 0; sn < 4; ++sn)                \
                    acc[sm][sn] = __builtin_amdgcn_mfma_f32_16x16x32_f16(       \
                        af[sm], bf[sn], acc[sm][sn], 0, 0, 0);                  \
        }                                                                       \
        __syncthreads();   /* drains vmcnt -> next buf ready; reads done */     \
        cur ^= 1;                                                               \
    }

// QKV: A = xh [4096][1024], B = Wt [3072][1024]. grid (32, 24), 512 thr.
// Q output pre-scaled by (1/sqrt(Dh))*log2(e) -> attention uses raw exp2.
// XCD swizzle: 768 blocks -> 8 chunks of 96 (32 row-tiles x 3 col-panels).
__global__ __launch_bounds__(512) void qkv_gemm_kernel(
    const _Float16* __restrict__ xh, const _Float16* __restrict__ Wt,
    const float* __restrict__ bq, const float* __restrict__ bk, const float* __restrict__ bv,
    _Float16* __restrict__ qh, _Float16* __restrict__ kh, _Float16* __restrict__ vt)
{
    const int lin = blockIdx.y * 32 + blockIdx.x;      // dispatch-linear id
    const int swz = (lin & 7) * 96 + (lin >> 3);       // bijective (768%8==0)
    GEMM_MAIN8(xh, Wt, 1024, 1024, 1024, (swz & 31), (swz >> 5))

    const int m = colBase >> 10;            // 0=Q,1=K,2=V
    const int nIn = colBase & 1023;
    const float* __restrict__ bias = (m == 0) ? bq : (m == 1) ? bk : bv;
    const float sc_ = (m == 0) ? 0.1803368801f : 1.0f;   // 0.125 * log2(e)

    if (m < 2) {
        _Float16* __restrict__ out = (m == 0) ? qh : kh;
#pragma unroll
        for (int sn = 0; sn < 4; ++sn) {
            int n = nIn + wcc + sn * 16 + l15;
            int hh = n >> 6, e = n & 63;
            float bv_ = bias[n];
#pragma unroll
            for (int sm = 0; sm < 2; ++sm)
#pragma unroll
                for (int reg = 0; reg < 4; ++reg) {
                    int t = rowBase + wrr + sm * 16 + quad * 4 + reg;
                    int bb = t >> 11, tt = t & (TT - 1);
                    out[(((size_t)bb * HH + hh) * TT + tt) * DH + e] =
                        (_Float16)((acc[sm][sn][reg] + bv_) * sc_);
                }
        }
    } else {
#pragma unroll
        for (int sn = 0; sn < 4; ++sn) {
            int n = nIn + wcc + sn * 16 + l15;
            int hh = n >> 6, e = n & 63;
            float bv_ = bias[n];
#pragma unroll
            for (int sm = 0; sm < 2; ++sm) {
                int t = rowBase + wrr + sm * 16 + quad * 4;
                int bb = t >> 11, tt = t & (TT - 1);
                int tile = tt >> 6, tp = tt & 63;
                half4v o;
#pragma unroll
                for (int reg = 0; reg < 4; ++reg)
                    o[reg] = (_Float16)(acc[sm][sn][reg] + bv_);
                *(half4v*)&vt[(((size_t)bb * HH + hh) * 32 + tile) * 4096 +
                              (size_t)e * 64 + tp] = o;
            }
        }
    }
}

// out-proj: A = zh [4096][1024], B = Wot [1024][1024]. grid (32, 8), 512 thr.
__global__ __launch_bounds__(512) void out_gemm_kernel(
    const _Float16* __restrict__ zh, const _Float16* __restrict__ Wot,
    const float* __restrict__ bo, float* __restrict__ out)
{
    const int lin = blockIdx.y * 32 + blockIdx.x;      // 0..255
    const int swz = (lin & 7) * 32 + (lin >> 3);       // bijective (256%8==0)
    GEMM_MAIN8(zh, Wot, 1024, 1024, 1024, (swz & 31), (swz >> 5))

#pragma unroll
    for (int sn = 0; sn < 4; ++sn) {
        int d = colBase + wcc + sn * 16 + l15;
        float b_ = bo[d];
#pragma unroll
        for (int sm = 0; sm < 2; ++sm)
#pragma unroll
            for (int reg = 0; reg < 4; ++reg) {
                int r = rowBase + wrr + sm * 16 + quad * 4 + reg;
                out[(size_t)r * 1024 + d] = acc[sm][sn][reg] + b_;
            }
    }
}

// ---------------------------------------------------------------------------
// Causal flash attention (round-1 proven structure, setprio removed --
// barrier-locked 16-wave blocks are GEMM-like, where setprio measured
// negative): fp16 MFMA, 1024 threads (16 waves = 4/SIMD), 1 block/CU.
//  - 512 one-tile blocks, heavy-first (tile = 15 - bx>>5).
//  - split-K: waves 0-7 even 64-col k-subtiles, waves 8-15 odd; merge at end.
//  - row-max via 4x DPP row_ror; log2-domain softmax; row-sum via MFMA-ones.
//  - quad-buffered K/V via global_load_lds; prefetch before compute.
//  - NOTE round-2 lesson: 2 blocks/CU is register-infeasible (unified
//    VGPR+AGPR 64/wave forces massive scratch spill).
// LDS: qs 16K | ks 2x16K | vs 2x16K | ps 2x18K = 116 KB -> 1 block/CU.
// ---------------------------------------------------------------------------
#define ATTN_LDS (16384 + 32768 + 32768 + 2 * 18432)

__device__ __forceinline__ float rowmax16(float m) {
    int x;
    x = __builtin_amdgcn_update_dpp(__float_as_int(m), __float_as_int(m),
                                    0x121, 0xf, 0xf, false);   // row_ror:1
    m = fmaxf(m, __int_as_float(x));
    x = __builtin_amdgcn_update_dpp(__float_as_int(m), __float_as_int(m),
                                    0x122, 0xf, 0xf, false);   // row_ror:2
    m = fmaxf(m, __int_as_float(x));
    x = __builtin_amdgcn_update_dpp(__float_as_int(m), __float_as_int(m),
                                    0x124, 0xf, 0xf, false);   // row_ror:4
    m = fmaxf(m, __int_as_float(x));
    x = __builtin_amdgcn_update_dpp(__float_as_int(m), __float_as_int(m),
                                    0x128, 0xf, 0xf, false);   // row_ror:8
    m = fmaxf(m, __int_as_float(x));
    return m;
}

__global__ __launch_bounds__(1024) void attn_kernel(
    const _Float16* __restrict__ qh, const _Float16* __restrict__ kh,
    const _Float16* __restrict__ vt, _Float16* __restrict__ zh)
{
    __shared__ __align__(16) char smem[ATTN_LDS];
    _Float16* qs = (_Float16*)smem;                    // [128][64] swizzled
    _Float16* ks = (_Float16*)(smem + 16384);          // [4][64][64] swizzled
    _Float16* vs = (_Float16*)(smem + 49152);          // [4][64][64] swizzled
    float* accB = (float*)(smem + 16384);              // merge scratch (32 KB)
    float* mlB  = (float*)(smem + 49152);              // merge scratch (1 KB)

    const int tid  = threadIdx.x;          // 0..1023
    const int wave = tid >> 6;             // 0..15
    const int lane = tid & 63;
    const int quad = lane >> 4;
    const int l15  = lane & 15;
    const int g    = wave >> 3;            // split-K group
    const int wr   = wave & 7;             // 16-row strip

    const int bx   = blockIdx.x;           // 0..511
    const int tile = 15 - (bx >> 5);       // heavy-first dispatch order
    const int idx  = bx & 31;
    const int h    = idx & 15;
    const int b    = idx >> 4;

    const int Q0 = tile * 128;
    const int niter = tile + 1;

    _Float16* ps = (_Float16*)(smem + 81920 + g * 18432);  // [128][72] padded

    const size_t headBase = ((size_t)b * HH + h) * (size_t)(TT * DH);
    const _Float16* qp  = qh + headBase + (size_t)Q0 * 64;
    const _Float16* kp  = kh + headBase;
    const _Float16* vtp = vt + ((size_t)b * HH + h) * 32 * 4096;

    half8 ones;
#pragma unroll
    for (int i = 0; i < 8; ++i) ones[i] = (_Float16)1.0f;

    // staging geometry: 1024 threads x 16B = 128 rows x 64 halfs, swizzled src
    const int srow = tid >> 3, sc8 = tid & 7;
    const size_t soff = (size_t)srow * 64 + ((sc8 ^ (srow & 7)) << 3);

    // stage k-rows [s*128, s*128+128) of K and V into parity (s&1)
    auto stage_kv = [&](int s) {
        GLOAD(kp + (size_t)s * 8192 + soff, &ks[(s & 1) * 8192 + wave * 512]);
        GLOAD(vtp + (size_t)s * 8192 + soff, &vs[(s & 1) * 8192 + wave * 512]);
    };

    // stage Q (16 KB) + first K/V pair
    GLOAD(qp + soff, &qs[wave * 512]);
    stage_kv(0);
    __syncthreads();

    // hoisted Q A-frags (wave's strip)
    const int rmq = wr * 16 + l15;
    const int swq = rmq & 7;
    half8 aq0 = *(const half8*)&qs[rmq * 64 + ((quad ^ swq) << 3)];
    half8 aq1 = *(const half8*)&qs[rmq * 64 + (((4 + quad) ^ swq) << 3)];

    f32x4 accO[4];
    float mrow[4], lsum[4];
#pragma unroll
    for (int j = 0; j < 4; ++j) {
        accO[j] = f32x4{0.f, 0.f, 0.f, 0.f};
        mrow[j] = -1e30f;
        lsum[j] = 0.f;
    }

    for (int s = 0; s < niter; ++s) {
        if (s + 1 < niter) stage_kv(s + 1);

        const _Float16* curK = &ks[((s & 1) * 2 + g) * 4096];
        const _Float16* curV = &vs[((s & 1) * 2 + g) * 4096];
        const int tileC0 = s * 128 + g * 64;

        // K B-frags
        half8 bk0[4], bk1[4];
#pragma unroll
        for (int j = 0; j < 4; ++j) {
            int rn = j * 16 + l15, sw = rn & 7;
            bk0[j] = *(const half8*)&curK[rn * 64 + ((quad ^ sw) << 3)];
            bk1[j] = *(const half8*)&curK[rn * 64 + (((4 + quad) ^ sw) << 3)];
        }

        // S = Q K^T (log2-domain logits)
        f32x4 S[4];
#pragma unroll
        for (int j = 0; j < 4; ++j) {
            f32x4 a = f32x4{0.f, 0.f, 0.f, 0.f};
            a = __builtin_amdgcn_mfma_f32_16x16x32_f16(aq0, bk0[j], a, 0, 0, 0);
            a = __builtin_amdgcn_mfma_f32_16x16x32_f16(aq1, bk1[j], a, 0, 0, 0);
            S[j] = a;
        }

        // causal mask (near-diagonal strips only)
        const int rowMin = Q0 + wr * 16;
        if (tileC0 + 63 > rowMin) {
#pragma unroll
            for (int j = 0; j < 4; ++j) {
                int col = tileC0 + j * 16 + l15;
#pragma unroll
                for (int reg = 0; reg < 4; ++reg)
                    if (col > rowMin + quad * 4 + reg) S[j][reg] = -1e30f;
            }
        }

        // online softmax (exp2 domain, DPP row-max)
#pragma unroll
        for (int reg = 0; reg < 4; ++reg) {
            float mt = fmaxf(fmaxf(S[0][reg], S[1][reg]),
                             fmaxf(S[2][reg], S[3][reg]));
            mt = rowmax16(mt);
            float mnew = fmaxf(mrow[reg], mt);
            float alpha = __builtin_amdgcn_exp2f(mrow[reg] - mnew);
            mrow[reg] = mnew;
            lsum[reg] *= alpha;
#pragma unroll
            for (int j = 0; j < 4; ++j) {
                float sv = S[j][reg];
                float pv = __builtin_amdgcn_exp2f(sv - mnew);
                pv = (sv < -5e29f) ? 0.f : pv;   // all-masked-tile guard
                S[j][reg] = pv;
                accO[j][reg] *= alpha;
            }
        }
        const int prow = wr * 16 + quad * 4;
#pragma unroll
        for (int j = 0; j < 4; ++j)
#pragma unroll
            for (int reg = 0; reg < 4; ++reg)
                ps[(prow + reg) * 72 + j * 16 + l15] = (_Float16)S[j][reg];

        // P A-frags (padded ps; per-wave DS ordering guarantees visibility)
        half8 ap0 = *(const half8*)&ps[rmq * 72 + quad * 8];
        half8 ap1 = *(const half8*)&ps[rmq * 72 + 32 + quad * 8];

        // row-sum via MFMA-by-ones
        {
            f32x4 psum = f32x4{0.f, 0.f, 0.f, 0.f};
            psum = __builtin_amdgcn_mfma_f32_16x16x32_f16(ap0, ones, psum, 0, 0, 0);
            psum = __builtin_amdgcn_mfma_f32_16x16x32_f16(ap1, ones, psum, 0, 0, 0);
#pragma unroll
            for (int reg = 0; reg < 4; ++reg) lsum[reg] += psum[reg];
        }

        // O += P V
#pragma unroll
        for (int j = 0; j < 4; ++j) {
            int rn = j * 16 + l15, sw = rn & 7;
            half8 bv0 = *(const half8*)&curV[rn * 64 + ((quad ^ sw) << 3)];
            half8 bv1 = *(const half8*)&curV[rn * 64 + (((4 + quad) ^ sw) << 3)];
            accO[j] = __builtin_amdgcn_mfma_f32_16x16x32_f16(ap0, bv0, accO[j], 0, 0, 0);
            accO[j] = __builtin_amdgcn_mfma_f32_16x16x32_f16(ap1, bv1, accO[j], 0, 0, 0);
        }

        __syncthreads();   // drains prefetch; protects buffer reuse
    }

    // ---- merge the two split-K states and store ----
    const int r0 = wr * 16 + quad * 4;
    if (g == 1) {
#pragma unroll
        for (int j = 0; j < 4; ++j)
#pragma unroll
            for (int reg = 0; reg < 4; ++reg)
                accB[(r0 + reg) * 64 + j * 16 + l15] = accO[j][reg];
        if (l15 == 0) {
#pragma unroll
            for (int reg = 0; reg < 4; ++reg) {
                mlB[r0 + reg] = mrow[reg];
                mlB[128 + r0 + reg] = lsum[reg];
            }
        }
    }
    __syncthreads();
    if (g == 0) {
#pragma unroll
        for (int reg = 0; reg < 4; ++reg) {
            const int r = r0 + reg;
            float mb = mlB[r], lb = mlB[128 + r];
            float m = fmaxf(mrow[reg], mb);
            float ea = __builtin_amdgcn_exp2f(mrow[reg] - m);
            float eb = __builtin_amdgcn_exp2f(mb - m);
            float inv = 1.f / (ea * lsum[reg] + eb * lb);
            int t = Q0 + r;
            size_t rowOff = ((size_t)b * TT + t) * DD + h * DH;
#pragma unroll
            for (int j = 0; j < 4; ++j) {
                float ob = accB[r * 64 + j * 16 + l15];
                zh[rowOff + j * 16 + l15] =
                    (_Float16)((ea * accO[j][reg] + eb * ob) * inv);
            }
        }
    }
}

extern "C" void kernel_launch(void* const* d_in, const int* in_sizes, int n_in,
                              void* d_out, int out_size, void* d_ws, size_t ws_size,
                              hipStream_t stream) {
    const float* x  = (const float*)d_in[0];
    const float* Wq = (const float*)d_in[1];
    const float* Wk = (const float*)d_in[2];
    const float* Wv = (const float*)d_in[3];
    const float* Wo = (const float*)d_in[4];
    const float* bq = (const float*)d_in[5];
    const float* bk = (const float*)d_in[6];
    const float* bv = (const float*)d_in[7];
    const float* bo = (const float*)d_in[8];
    float* out = (float*)d_out;

    const size_t MB = 1u << 20;
    char* wsb = (char*)d_ws;
    _Float16* xh  = (_Float16*)(wsb + 0 * MB);    //  8 MB  [4096][1024]
    _Float16* Wt  = (_Float16*)(wsb + 8 * MB);    //  6 MB  [3072][1024]
    _Float16* Wot = (_Float16*)(wsb + 14 * MB);   //  2 MB  [1024][1024]
    _Float16* qh  = (_Float16*)(wsb + 16 * MB);   //  8 MB  [b][h][t][e] (log2-domain scale)
    _Float16* kh  = (_Float16*)(wsb + 24 * MB);   //  8 MB
    _Float16* vt  = (_Float16*)(wsb + 32 * MB);   //  8 MB  [b][h][tile][e][t']
    _Float16* zh  = (_Float16*)(wsb + 40 * MB);   //  8 MB  [4096][1024]

    cvt_all_kernel<<<3072, 256, 0, stream>>>(x, Wq, Wk, Wv, Wo, xh, Wt, Wot);
    qkv_gemm_kernel<<<dim3(32, 24), 512, 0, stream>>>(xh, Wt, bq, bk, bv, qh, kh, vt);
    attn_kernel<<<512, 1024, 0, stream>>>(qh, kh, vt, zh);
    out_gemm_kernel<<<dim3(32, 8), 512, 0, stream>>>(zh, Wot, bo, out);
}

// Round 6
// 182.479 us; speedup vs baseline: 1.5634x; 1.0278x over previous
//
#include <hip/hip_runtime.h>

#define BB 2
#define HH 16
#define TT 2048
#define DD 1024
#define DH 64

typedef _Float16 half8 __attribute__((ext_vector_type(8)));
typedef _Float16 half4v __attribute__((ext_vector_type(4)));
typedef _Float16 half2v __attribute__((ext_vector_type(2)));
typedef float f32x4 __attribute__((ext_vector_type(4)));

#define GLOAD(g, l)                                                        \
    __builtin_amdgcn_global_load_lds(                                      \
        (const __attribute__((address_space(1))) unsigned int*)(g),        \
        (__attribute__((address_space(3))) unsigned int*)(l), 16, 0, 0)

// ---------------------------------------------------------------------------
// Merged convert kernel (one launch instead of three).
//  blocks [0,2048):    x fp32 -> xh fp16 (flat)
//  blocks [2048,2816): W_{Q,K,V}[h][d][e] -> Wt[(m*1024+h*64+e)][d] fp16
//  blocks [2816,3072): W_output [he][d] -> Wot[d][he] fp16
// ---------------------------------------------------------------------------
__global__ __launch_bounds__(256) void cvt_all_kernel(
    const float* __restrict__ x, const float* __restrict__ Wq,
    const float* __restrict__ Wk, const float* __restrict__ Wv,
    const float* __restrict__ Wo, _Float16* __restrict__ xh,
    _Float16* __restrict__ Wt, _Float16* __restrict__ Wot)
{
    const int bid = blockIdx.x;
    const int tid = threadIdx.x;
    __shared__ float ts[64][68];

    if (bid < 2048) {
        size_t i = ((size_t)bid * 256 + tid) * 8;
        float4 a = *(const float4*)&x[i];
        float4 b = *(const float4*)&x[i + 4];
        half8 o;
        o[0] = (_Float16)a.x; o[1] = (_Float16)a.y; o[2] = (_Float16)a.z; o[3] = (_Float16)a.w;
        o[4] = (_Float16)b.x; o[5] = (_Float16)b.y; o[6] = (_Float16)b.z; o[7] = (_Float16)b.w;
        *(half8*)&xh[i] = o;
        return;
    }

    if (bid < 2816) {
        const int j = bid - 2048;
        const int m = j >> 8;              // 0..2
        const int rem = j & 255;
        const int h = rem >> 4;            // 0..15
        const int d0 = (rem & 15) * 64;
        const float* __restrict__ W = (m == 0) ? Wq : (m == 1) ? Wk : Wv;

        const int dr = tid >> 2, ec = (tid & 3) * 16;
        const float* p = W + ((size_t)h * DD + d0 + dr) * DH + ec;
        *(float4*)&ts[dr][ec + 0]  = *(const float4*)(p + 0);
        *(float4*)&ts[dr][ec + 4]  = *(const float4*)(p + 4);
        *(float4*)&ts[dr][ec + 8]  = *(const float4*)(p + 8);
        *(float4*)&ts[dr][ec + 12] = *(const float4*)(p + 12);
        __syncthreads();

        const int er = tid >> 2, dc = (tid & 3) * 16;
        size_t obase = ((size_t)m * 1024 + h * 64 + er) * 1024 + d0 + dc;
        half8 o;
#pragma unroll
        for (int jj = 0; jj < 8; ++jj) o[jj] = (_Float16)ts[dc + jj][er];
        *(half8*)&Wt[obase] = o;
#pragma unroll
        for (int jj = 0; jj < 8; ++jj) o[jj] = (_Float16)ts[dc + 8 + jj][er];
        *(half8*)&Wt[obase + 8] = o;
        return;
    }

    {
        const int j = bid - 2816;
        const int r0 = (j & 15) * 64;      // he
        const int c0 = (j >> 4) * 64;      // d

        const int rr = tid >> 2, cc = (tid & 3) * 16;
        const float* p = Wo + (size_t)(r0 + rr) * 1024 + c0 + cc;
        *(float4*)&ts[rr][cc + 0]  = *(const float4*)(p + 0);
        *(float4*)&ts[rr][cc + 4]  = *(const float4*)(p + 4);
        *(float4*)&ts[rr][cc + 8]  = *(const float4*)(p + 8);
        *(float4*)&ts[rr][cc + 12] = *(const float4*)(p + 12);
        __syncthreads();

        const int er = tid >> 2, dc = (tid & 3) * 16;
        size_t obase = (size_t)(c0 + er) * 1024 + r0 + dc;
        half8 o;
#pragma unroll
        for (int jj = 0; jj < 8; ++jj) o[jj] = (_Float16)ts[dc + jj][er];
        *(half8*)&Wot[obase] = o;
#pragma unroll
        for (int jj = 0; jj < 8; ++jj) o[jj] = (_Float16)ts[dc + 8 + jj][er];
        *(half8*)&Wot[obase + 8] = o;
    }
}

// ---------------------------------------------------------------------------
// MFMA GEMM core v2 (proven round-4): 128x128 tile, BK=64, 512 threads,
// 2-phase double-buffered global_load_lds staging; one barrier per K-step.
// Wave owns 32x64 -> acc[2][4]. LDS 64 KB -> 2 blocks/CU for qkv.
// ---------------------------------------------------------------------------
#define GEMM_MAIN8(Aptr, Bptr, lda, ldb, KDIM, RB, CB)                          \
    __shared__ _Float16 As[2][128 * 64];                                        \
    __shared__ _Float16 Bs[2][128 * 64];                                        \
    const int tid = threadIdx.x;                                                \
    const int wave = tid >> 6, lane = tid & 63;                                 \
    const int quad = lane >> 4, l15 = lane & 15;                                \
    const int rowBase = (RB) * 128;                                             \
    const int colBase = (CB) * 128;                                             \
    const int wrr = (wave >> 1) * 32, wcc = (wave & 1) * 64;                    \
    f32x4 acc[2][4];                                                            \
    _Pragma("unroll") for (int sm = 0; sm < 2; ++sm)                            \
        _Pragma("unroll") for (int sn = 0; sn < 4; ++sn)                        \
            acc[sm][sn] = f32x4{0.f, 0.f, 0.f, 0.f};                            \
    const int srow_[2] = { tid >> 3, (512 + tid) >> 3 };                        \
    const int sc8_ = tid & 7;                                                   \
    _Pragma("unroll") for (int pass = 0; pass < 2; ++pass) {                    \
        int row = srow_[pass];                                                  \
        int sc = ((sc8_ ^ (row & 7)) << 3);                                     \
        GLOAD((Aptr) + (size_t)(rowBase + row) * (lda) + sc,                    \
              &As[0][(pass * 512 + tid) * 8]);                                  \
        GLOAD((Bptr) + (size_t)(colBase + row) * (ldb) + sc,                    \
              &Bs[0][(pass * 512 + tid) * 8]);                                  \
    }                                                                           \
    __syncthreads();                                                            \
    int cur = 0;                                                                \
    for (int k0 = 0; k0 < (KDIM); k0 += 64) {                                   \
        if (k0 + 64 < (KDIM)) {                                                 \
            _Pragma("unroll") for (int pass = 0; pass < 2; ++pass) {            \
                int row = srow_[pass];                                          \
                int sc = ((sc8_ ^ (row & 7)) << 3);                             \
                GLOAD((Aptr) + (size_t)(rowBase + row) * (lda) + k0 + 64 + sc,  \
                      &As[cur ^ 1][(pass * 512 + tid) * 8]);                    \
                GLOAD((Bptr) + (size_t)(colBase + row) * (ldb) + k0 + 64 + sc,  \
                      &Bs[cur ^ 1][(pass * 512 + tid) * 8]);                    \
            }                                                                   \
        }                                                                       \
        _Pragma("unroll") for (int kk = 0; kk < 2; ++kk) {                      \
            half8 af[2], bf[4];                                                 \
            _Pragma("unroll") for (int s = 0; s < 2; ++s) {                     \
                int rm = wrr + s * 16 + l15;                                    \
                af[s] = *(const half8*)&As[cur][rm * 64 +                       \
                        (((kk * 4 + quad) ^ (rm & 7)) << 3)];                   \
            }                                                                   \
            _Pragma("unroll") for (int s = 0; s < 4; ++s) {                     \
                int rn = wcc + s * 16 + l15;                                    \
                bf[s] = *(const half8*)&Bs[cur][rn * 64 +                       \
                        (((kk * 4 + quad) ^ (rn & 7)) << 3)];                   \
            }                                                                   \
            _Pragma("unroll") for (int sm = 0; sm < 2; ++sm)                    \
                _Pragma("unroll") for (int sn = 0; sn < 4; ++sn)                \
                    acc[sm][sn] = __builtin_amdgcn_mfma_f32_16x16x32_f16(       \
                        af[sm], bf[sn], acc[sm][sn], 0, 0, 0);                  \
        }                                                                       \
        __syncthreads();                                                        \
        cur ^= 1;                                                               \
    }

// ---------------------------------------------------------------------------
// MFMA GEMM core small-tile: 64x128 tile, BK=64, 512 threads, dbuf staging.
// LDS 48 KB -> 2 blocks/CU at grid 512 (out_gemm occupancy fix: 8->16
// waves/CU). Wave owns 32x32 -> acc[2][2].
// ---------------------------------------------------------------------------
#define GEMM_MAIN_S(Aptr, Bptr, lda, ldb, KDIM, RB, CB)                         \
    __shared__ _Float16 As[2][64 * 64];                                         \
    __shared__ _Float16 Bs[2][128 * 64];                                        \
    const int tid = threadIdx.x;                                                \
    const int wave = tid >> 6, lane = tid & 63;                                 \
    const int quad = lane >> 4, l15 = lane & 15;                                \
    const int rowBase = (RB) * 64;                                              \
    const int colBase = (CB) * 128;                                             \
    const int wrr = (wave >> 2) * 32, wcc = (wave & 3) * 32;                    \
    f32x4 acc[2][2];                                                            \
    _Pragma("unroll") for (int sm = 0; sm < 2; ++sm)                            \
        _Pragma("unroll") for (int sn = 0; sn < 2; ++sn)                        \
            acc[sm][sn] = f32x4{0.f, 0.f, 0.f, 0.f};                            \
    const int srowA = tid >> 3, sc8_ = tid & 7;                                 \
    {                                                                           \
        int scA = ((sc8_ ^ (srowA & 7)) << 3);                                  \
        GLOAD((Aptr) + (size_t)(rowBase + srowA) * (lda) + scA,                 \
              &As[0][tid * 8]);                                                 \
        _Pragma("unroll") for (int pass = 0; pass < 2; ++pass) {                \
            int row = pass * 64 + srowA;                                        \
            int sc = ((sc8_ ^ (row & 7)) << 3);                                 \
            GLOAD((Bptr) + (size_t)(colBase + row) * (ldb) + sc,                \
                  &Bs[0][(pass * 512 + tid) * 8]);                              \
        }                                                                       \
    }                                                                           \
    __syncthreads();                                                            \
    int cur = 0;                                                                \
    for (int k0 = 0; k0 < (KDIM); k0 += 64) {                                   \
        if (k0 + 64 < (KDIM)) {                                                 \
            int scA = ((sc8_ ^ (srowA & 7)) << 3);                              \
            GLOAD((Aptr) + (size_t)(rowBase + srowA) * (lda) + k0 + 64 + scA,   \
                  &As[cur ^ 1][tid * 8]);                                       \
            _Pragma("unroll") for (int pass = 0; pass < 2; ++pass) {            \
                int row = pass * 64 + srowA;                                    \
                int sc = ((sc8_ ^ (row & 7)) << 3);                             \
                GLOAD((Bptr) + (size_t)(colBase + row) * (ldb) + k0 + 64 + sc,  \
                      &Bs[cur ^ 1][(pass * 512 + tid) * 8]);                    \
            }                                                                   \
        }                                                                       \
        _Pragma("unroll") for (int kk = 0; kk < 2; ++kk) {                      \
            half8 af[2], bf[2];                                                 \
            _Pragma("unroll") for (int s = 0; s < 2; ++s) {                     \
                int rm = wrr + s * 16 + l15;                                    \
                af[s] = *(const half8*)&As[cur][rm * 64 +                       \
                        (((kk * 4 + quad) ^ (rm & 7)) << 3)];                   \
                int rn = wcc + s * 16 + l15;                                    \
                bf[s] = *(const half8*)&Bs[cur][rn * 64 +                       \
                        (((kk * 4 + quad) ^ (rn & 7)) << 3)];                   \
            }                                                                   \
            _Pragma("unroll") for (int sm = 0; sm < 2; ++sm)                    \
                _Pragma("unroll") for (int sn = 0; sn < 2; ++sn)                \
                    acc[sm][sn] = __builtin_amdgcn_mfma_f32_16x16x32_f16(       \
                        af[sm], bf[sn], acc[sm][sn], 0, 0, 0);                  \
        }                                                                       \
        __syncthreads();                                                        \
        cur ^= 1;                                                               \
    }

// QKV: A = xh [4096][1024], B = Wt [3072][1024]. grid (32, 24), 512 thr.
// Q output pre-scaled by (1/sqrt(Dh))*log2(e) -> attention uses raw exp2.
__global__ __launch_bounds__(512) void qkv_gemm_kernel(
    const _Float16* __restrict__ xh, const _Float16* __restrict__ Wt,
    const float* __restrict__ bq, const float* __restrict__ bk, const float* __restrict__ bv,
    _Float16* __restrict__ qh, _Float16* __restrict__ kh, _Float16* __restrict__ vt)
{
    const int lin = blockIdx.y * 32 + blockIdx.x;      // dispatch-linear id
    const int swz = (lin & 7) * 96 + (lin >> 3);       // bijective (768%8==0)
    GEMM_MAIN8(xh, Wt, 1024, 1024, 1024, (swz & 31), (swz >> 5))

    const int m = colBase >> 10;            // 0=Q,1=K,2=V
    const int nIn = colBase & 1023;
    const float* __restrict__ bias = (m == 0) ? bq : (m == 1) ? bk : bv;
    const float sc_ = (m == 0) ? 0.1803368801f : 1.0f;   // 0.125 * log2(e)

    if (m < 2) {
        _Float16* __restrict__ out = (m == 0) ? qh : kh;
#pragma unroll
        for (int sn = 0; sn < 4; ++sn) {
            int n = nIn + wcc + sn * 16 + l15;
            int hh = n >> 6, e = n & 63;
            float bv_ = bias[n];
#pragma unroll
            for (int sm = 0; sm < 2; ++sm)
#pragma unroll
                for (int reg = 0; reg < 4; ++reg) {
                    int t = rowBase + wrr + sm * 16 + quad * 4 + reg;
                    int bb = t >> 11, tt = t & (TT - 1);
                    out[(((size_t)bb * HH + hh) * TT + tt) * DH + e] =
                        (_Float16)((acc[sm][sn][reg] + bv_) * sc_);
                }
        }
    } else {
#pragma unroll
        for (int sn = 0; sn < 4; ++sn) {
            int n = nIn + wcc + sn * 16 + l15;
            int hh = n >> 6, e = n & 63;
            float bv_ = bias[n];
#pragma unroll
            for (int sm = 0; sm < 2; ++sm) {
                int t = rowBase + wrr + sm * 16 + quad * 4;
                int bb = t >> 11, tt = t & (TT - 1);
                int tile = tt >> 6, tp = tt & 63;
                half4v o;
#pragma unroll
                for (int reg = 0; reg < 4; ++reg)
                    o[reg] = (_Float16)(acc[sm][sn][reg] + bv_);
                *(half4v*)&vt[(((size_t)bb * HH + hh) * 32 + tile) * 4096 +
                              (size_t)e * 64 + tp] = o;
            }
        }
    }
}

// out-proj: A = zh [4096][1024], B = Wot [1024][1024]. 64x128 tiles,
// grid 512 (1-D), 512 thr -> 2 blocks/CU, 16 waves/CU. XCD swizzle: each
// XCD owns one full 128-col panel (B slab 256 KB, L2-resident).
__global__ __launch_bounds__(512) void out_gemm_kernel(
    const _Float16* __restrict__ zh, const _Float16* __restrict__ Wot,
    const float* __restrict__ bo, float* __restrict__ out)
{
    const int lin = blockIdx.x;                        // 0..511
    const int swz = (lin & 7) * 64 + (lin >> 3);       // bijective (512%8==0)
    GEMM_MAIN_S(zh, Wot, 1024, 1024, 1024, (swz & 63), (swz >> 6))

#pragma unroll
    for (int sn = 0; sn < 2; ++sn) {
        int d = colBase + wcc + sn * 16 + l15;
        float b_ = bo[d];
#pragma unroll
        for (int sm = 0; sm < 2; ++sm)
#pragma unroll
            for (int reg = 0; reg < 4; ++reg) {
                int r = rowBase + wrr + sm * 16 + quad * 4 + reg;
                out[(size_t)r * 1024 + d] = acc[sm][sn][reg] + b_;
            }
    }
}

// ---------------------------------------------------------------------------
// Causal flash attention v5: swapped-QK^T (T12-family) softmax.
//  - S^T = mfma(K_frag, Q_frag): A/B frags share one physical layout, so the
//    swap is argument order only. Lane owns ONE q-row (n=l15), 16 k-values
//    (m=quad*4+reg across 4 j-tiles).
//  - row-max: 15 in-lane fmax + 2 shfl_xor (replaces 4x DPP ladders).
//  - defer-max (T13, THR=8 in log2 domain): rescale only when
//    __any(mt > m+8); alpha==1.0 exactly for non-rescaled rows.
//  - P pack: 8 cvt_pkrtz + 4 ds_write_b64 (consecutive regs = consecutive k)
//    replaces 16 cvt + 16 ds_write_b16.
//  - rowsum via MFMA-by-ones (unchanged); accO/lsum stay in C-layout via 4
//    shfl alpha/max broadcasts.
//  - structure otherwise round-1: 1024 thr, split-K waves 0-7/8-15, heavy-
//    first tiles, quad-buffered K/V global_load_lds prefetch, 1 block/CU.
// LDS: qs 16K | ks 2x16K | vs 2x16K | ps 2x18K = 116 KB.
// ---------------------------------------------------------------------------
#define ATTN_LDS (16384 + 32768 + 32768 + 2 * 18432)

__global__ __launch_bounds__(1024) void attn_kernel(
    const _Float16* __restrict__ qh, const _Float16* __restrict__ kh,
    const _Float16* __restrict__ vt, _Float16* __restrict__ zh)
{
    __shared__ __align__(16) char smem[ATTN_LDS];
    _Float16* qs = (_Float16*)smem;                    // [128][64] swizzled
    _Float16* ks = (_Float16*)(smem + 16384);          // [4][64][64] swizzled
    _Float16* vs = (_Float16*)(smem + 49152);          // [4][64][64] swizzled
    float* accB = (float*)(smem + 16384);              // merge scratch (32 KB)
    float* mlB  = (float*)(smem + 49152);              // merge scratch (1 KB)

    const int tid  = threadIdx.x;          // 0..1023
    const int wave = tid >> 6;             // 0..15
    const int lane = tid & 63;
    const int quad = lane >> 4;
    const int l15  = lane & 15;
    const int g    = wave >> 3;            // split-K group
    const int wr   = wave & 7;             // 16-row strip

    const int bx   = blockIdx.x;           // 0..511
    const int tile = 15 - (bx >> 5);       // heavy-first dispatch order
    const int idx  = bx & 31;
    const int h    = idx & 15;
    const int b    = idx >> 4;

    const int Q0 = tile * 128;
    const int niter = tile + 1;

    _Float16* ps = (_Float16*)(smem + 81920 + g * 18432);  // [128][72] padded

    const size_t headBase = ((size_t)b * HH + h) * (size_t)(TT * DH);
    const _Float16* qp  = qh + headBase + (size_t)Q0 * 64;
    const _Float16* kp  = kh + headBase;
    const _Float16* vtp = vt + ((size_t)b * HH + h) * 32 * 4096;

    half8 ones;
#pragma unroll
    for (int i = 0; i < 8; ++i) ones[i] = (_Float16)1.0f;

    // staging geometry: 1024 threads x 16B = 128 rows x 64 halfs, swizzled src
    const int srow = tid >> 3, sc8 = tid & 7;
    const size_t soff = (size_t)srow * 64 + ((sc8 ^ (srow & 7)) << 3);

    // stage k-rows [s*128, s*128+128) of K and V into parity (s&1)
    auto stage_kv = [&](int s) {
        GLOAD(kp + (size_t)s * 8192 + soff, &ks[(s & 1) * 8192 + wave * 512]);
        GLOAD(vtp + (size_t)s * 8192 + soff, &vs[(s & 1) * 8192 + wave * 512]);
    };

    // stage Q (16 KB) + first K/V pair
    GLOAD(qp + soff, &qs[wave * 512]);
    stage_kv(0);
    __syncthreads();

    // hoisted Q frags (wave's strip); used as B-operand in swapped QK^T
    const int rmq = wr * 16 + l15;
    const int swq = rmq & 7;
    half8 aq0 = *(const half8*)&qs[rmq * 64 + ((quad ^ swq) << 3)];
    half8 aq1 = *(const half8*)&qs[rmq * 64 + (((4 + quad) ^ swq) << 3)];

    f32x4 accO[4];
    float lsum[4];
    float mrowL = -1e30f;                  // running max of row (wr*16 + l15)
#pragma unroll
    for (int j = 0; j < 4; ++j) {
        accO[j] = f32x4{0.f, 0.f, 0.f, 0.f};
        lsum[j] = 0.f;
    }

    const int prowB = (wr * 16 + l15) * 72;   // this lane's P row base (halves)

    for (int s = 0; s < niter; ++s) {
        if (s + 1 < niter) stage_kv(s + 1);

        const _Float16* curK = &ks[((s & 1) * 2 + g) * 4096];
        const _Float16* curV = &vs[((s & 1) * 2 + g) * 4096];
        const int tileC0 = s * 128 + g * 64;

        // K frags (A-operand of swapped QK^T)
        half8 bk0[4], bk1[4];
#pragma unroll
        for (int j = 0; j < 4; ++j) {
            int rn = j * 16 + l15, sw = rn & 7;
            bk0[j] = *(const half8*)&curK[rn * 64 + ((quad ^ sw) << 3)];
            bk1[j] = *(const half8*)&curK[rn * 64 + (((4 + quad) ^ sw) << 3)];
        }

        // S^T = K Q^T: lane holds S[q=l15][k = tileC0 + j*16 + quad*4 + reg]
        f32x4 S[4];
#pragma unroll
        for (int j = 0; j < 4; ++j) {
            f32x4 a = f32x4{0.f, 0.f, 0.f, 0.f};
            a = __builtin_amdgcn_mfma_f32_16x16x32_f16(bk0[j], aq0, a, 0, 0, 0);
            a = __builtin_amdgcn_mfma_f32_16x16x32_f16(bk1[j], aq1, a, 0, 0, 0);
            S[j] = a;
        }

        // causal mask (near-diagonal strips only)
        const int rowMin = Q0 + wr * 16;
        const int rowAbs = rowMin + l15;
        if (tileC0 + 63 > rowMin) {
#pragma unroll
            for (int j = 0; j < 4; ++j) {
                int colB = tileC0 + j * 16 + quad * 4;
#pragma unroll
                for (int reg = 0; reg < 4; ++reg)
                    if (colB + reg > rowAbs) S[j][reg] = -1e30f;
            }
        }

        // row max: in-lane over 16, then cross-quad (lanes l15+16q)
        float mt = S[0][0];
#pragma unroll
        for (int j = 0; j < 4; ++j)
#pragma unroll
            for (int reg = 0; reg < 4; ++reg)
                if (j | reg) mt = fmaxf(mt, S[j][reg]);
        mt = fmaxf(mt, __shfl_xor(mt, 16));
        mt = fmaxf(mt, __shfl_xor(mt, 32));

        // defer-max: rescale only if some row's max grew past THR=8 (log2)
        bool resc = mt > mrowL + 8.0f;
        float mnew = resc ? mt : mrowL;
        if (__any(resc)) {
            float alpha = __builtin_amdgcn_exp2f(mrowL - mnew);  // ==1 if !resc
#pragma unroll
            for (int reg = 0; reg < 4; ++reg) {
                float aB = __shfl(alpha, quad * 4 + reg);
                lsum[reg] *= aB;
#pragma unroll
                for (int j = 0; j < 4; ++j) accO[j][reg] *= aB;
            }
        }
        mrowL = mnew;

        // P = exp2(S - m), pack pairs, 4x ds_write_b64 (row l15, cols 16j+4q)
#pragma unroll
        for (int j = 0; j < 4; ++j) {
            float p0, p1, p2, p3;
            {
                float sv = S[j][0]; p0 = __builtin_amdgcn_exp2f(sv - mnew);
                p0 = (sv < -5e29f) ? 0.f : p0;
                sv = S[j][1]; p1 = __builtin_amdgcn_exp2f(sv - mnew);
                p1 = (sv < -5e29f) ? 0.f : p1;
                sv = S[j][2]; p2 = __builtin_amdgcn_exp2f(sv - mnew);
                p2 = (sv < -5e29f) ? 0.f : p2;
                sv = S[j][3]; p3 = __builtin_amdgcn_exp2f(sv - mnew);
                p3 = (sv < -5e29f) ? 0.f : p3;
            }
            half2v lo = __builtin_bit_cast(half2v, __builtin_amdgcn_cvt_pkrtz(p0, p1));
            half2v hi = __builtin_bit_cast(half2v, __builtin_amdgcn_cvt_pkrtz(p2, p3));
            half4v w = { lo[0], lo[1], hi[0], hi[1] };
            *(half4v*)&ps[prowB + j * 16 + quad * 4] = w;
        }

        // P A-frags (padded ps; same-wave DS ordering guarantees visibility)
        half8 ap0 = *(const half8*)&ps[rmq * 72 + quad * 8];
        half8 ap1 = *(const half8*)&ps[rmq * 72 + 32 + quad * 8];

        // row-sum via MFMA-by-ones (C-layout rows quad*4+reg)
        {
            f32x4 psum = f32x4{0.f, 0.f, 0.f, 0.f};
            psum = __builtin_amdgcn_mfma_f32_16x16x32_f16(ap0, ones, psum, 0, 0, 0);
            psum = __builtin_amdgcn_mfma_f32_16x16x32_f16(ap1, ones, psum, 0, 0, 0);
#pragma unroll
            for (int reg = 0; reg < 4; ++reg) lsum[reg] += psum[reg];
        }

        // O += P V
#pragma unroll
        for (int j = 0; j < 4; ++j) {
            int rn = j * 16 + l15, sw = rn & 7;
            half8 bv0 = *(const half8*)&curV[rn * 64 + ((quad ^ sw) << 3)];
            half8 bv1 = *(const half8*)&curV[rn * 64 + (((4 + quad) ^ sw) << 3)];
            accO[j] = __builtin_amdgcn_mfma_f32_16x16x32_f16(ap0, bv0, accO[j], 0, 0, 0);
            accO[j] = __builtin_amdgcn_mfma_f32_16x16x32_f16(ap1, bv1, accO[j], 0, 0, 0);
        }

        __syncthreads();   // drains prefetch; protects buffer reuse
    }

    // broadcast per-row max into C-layout (row quad*4+reg within strip)
    float mB[4];
#pragma unroll
    for (int reg = 0; reg < 4; ++reg) mB[reg] = __shfl(mrowL, quad * 4 + reg);

    // ---- merge the two split-K states and store ----
    const int r0 = wr * 16 + quad * 4;
    if (g == 1) {
#pragma unroll
        for (int j = 0; j < 4; ++j)
#pragma unroll
            for (int reg = 0; reg < 4; ++reg)
                accB[(r0 + reg) * 64 + j * 16 + l15] = accO[j][reg];
        if (l15 == 0) {
#pragma unroll
            for (int reg = 0; reg < 4; ++reg) {
                mlB[r0 + reg] = mB[reg];
                mlB[128 + r0 + reg] = lsum[reg];
            }
        }
    }
    __syncthreads();
    if (g == 0) {
#pragma unroll
        for (int reg = 0; reg < 4; ++reg) {
            const int r = r0 + reg;
            float mb = mlB[r], lb = mlB[128 + r];
            float m = fmaxf(mB[reg], mb);
            float ea = __builtin_amdgcn_exp2f(mB[reg] - m);
            float eb = __builtin_amdgcn_exp2f(mb - m);
            float inv = 1.f / (ea * lsum[reg] + eb * lb);
            int t = Q0 + r;
            size_t rowOff = ((size_t)b * TT + t) * DD + h * DH;
#pragma unroll
            for (int j = 0; j < 4; ++j) {
                float ob = accB[r * 64 + j * 16 + l15];
                zh[rowOff + j * 16 + l15] =
                    (_Float16)((ea * accO[j][reg] + eb * ob) * inv);
            }
        }
    }
}

extern "C" void kernel_launch(void* const* d_in, const int* in_sizes, int n_in,
                              void* d_out, int out_size, void* d_ws, size_t ws_size,
                              hipStream_t stream) {
    const float* x  = (const float*)d_in[0];
    const float* Wq = (const float*)d_in[1];
    const float* Wk = (const float*)d_in[2];
    const float* Wv = (const float*)d_in[3];
    const float* Wo = (const float*)d_in[4];
    const float* bq = (const float*)d_in[5];
    const float* bk = (const float*)d_in[6];
    const float* bv = (const float*)d_in[7];
    const float* bo = (const float*)d_in[8];
    float* out = (float*)d_out;

    const size_t MB = 1u << 20;
    char* wsb = (char*)d_ws;
    _Float16* xh  = (_Float16*)(wsb + 0 * MB);    //  8 MB  [4096][1024]
    _Float16* Wt  = (_Float16*)(wsb + 8 * MB);    //  6 MB  [3072][1024]
    _Float16* Wot = (_Float16*)(wsb + 14 * MB);   //  2 MB  [1024][1024]
    _Float16* qh  = (_Float16*)(wsb + 16 * MB);   //  8 MB  [b][h][t][e] (log2-domain scale)
    _Float16* kh  = (_Float16*)(wsb + 24 * MB);   //  8 MB
    _Float16* vt  = (_Float16*)(wsb + 32 * MB);   //  8 MB  [b][h][tile][e][t']
    _Float16* zh  = (_Float16*)(wsb + 40 * MB);   //  8 MB  [4096][1024]

    cvt_all_kernel<<<3072, 256, 0, stream>>>(x, Wq, Wk, Wv, Wo, xh, Wt, Wot);
    qkv_gemm_kernel<<<dim3(32, 24), 512, 0, stream>>>(xh, Wt, bq, bk, bv, qh, kh, vt);
    attn_kernel<<<512, 1024, 0, stream>>>(qh, kh, vt, zh);
    out_gemm_kernel<<<512, 512, 0, stream>>>(zh, Wot, bo, out);
}